// Round 6
// baseline (1423.776 us; speedup 1.0000x reference)
//
#include <hip/hip_runtime.h>
#include <math.h>

#define BB    32
#define CCH   64
#define DIMN  1024
#define NCLS  10

typedef __attribute__((ext_vector_type(8))) short bf16x8;
typedef __attribute__((ext_vector_type(4))) float f32x4;
typedef __attribute__((ext_vector_type(4))) unsigned short us4;
typedef __attribute__((ext_vector_type(8))) unsigned short us8;

#define MFMA16(a, b, c) __builtin_amdgcn_mfma_f32_16x16x32_bf16(a, b, c, 0, 0, 0)

__device__ __forceinline__ unsigned short f2bf(float x) {
  unsigned u = __float_as_uint(x);
  unsigned r = u + 0x7fffu + ((u >> 16) & 1u);   // round-to-nearest-even
  return (unsigned short)(r >> 16);
}
__device__ __forceinline__ float bf2f(unsigned short h) {
  return __uint_as_float(((unsigned)h) << 16);
}
// x == h + m + l to ~2^-26 relative
__device__ __forceinline__ void split3(float x, unsigned short& h,
                                       unsigned short& m, unsigned short& l) {
  h = f2bf(x); float hf = bf2f(h);
  float r = x - hf;
  m = f2bf(r); float mf = bf2f(m);
  l = f2bf(r - mf);
}
__device__ __forceinline__ bf16x8 ld16B(const unsigned short* p) {
  union { us8 u; bf16x8 v; } c;
  c.u = *(const us8*)p;           // 16B-aligned -> ds_read_b128
  return c.v;
}

// ---------------------------------------------------------------------------
// 1) transpose: image (B,C,DIM) -> X (B,DIM,C)
// ---------------------------------------------------------------------------
__global__ __launch_bounds__(256) void k_transpose(const float* __restrict__ img,
                                                   float* __restrict__ X) {
  __shared__ float tile[64][65];
  const int b  = blockIdx.y;
  const int n0 = blockIdx.x * 64;
  const int tx = threadIdx.x & 63;
  const int ty = threadIdx.x >> 6;
  const float* src = img + (size_t)b * CCH * DIMN;
  #pragma unroll
  for (int c = ty; c < 64; c += 4)
    tile[c][tx] = src[(size_t)c * DIMN + n0 + tx];
  __syncthreads();
  float* dst = X + (size_t)b * DIMN * CCH;
  #pragma unroll
  for (int nn = ty; nn < 64; nn += 4)
    dst[(size_t)(n0 + nn) * CCH + tx] = tile[tx][nn];
}

// ---------------------------------------------------------------------------
// 2) QKV + per-layer pre-split (unchanged from r5: proven absmax 0.0):
//    Q fp32; K 3-term bf16 [t][c]; V 3-term bf16 transposed+tiled [b][kt][c][32]
// ---------------------------------------------------------------------------
__global__ __launch_bounds__(256) void k_qkv_split(
    const float* __restrict__ X,
    const float* __restrict__ WQ, const float* __restrict__ WK,
    const float* __restrict__ WV,
    float* __restrict__ Q,
    unsigned short* __restrict__ Kh, unsigned short* __restrict__ Km,
    unsigned short* __restrict__ Kl,
    unsigned short* __restrict__ VhT, unsigned short* __restrict__ VmT,
    unsigned short* __restrict__ VlT) {
  __shared__ float xs[16][64];
  __shared__ unsigned short vs[3][16][64];
  const int c  = threadIdx.x & 63;
  const int tg = threadIdx.x >> 6;
  const size_t t0 = (size_t)blockIdx.x * 16;
  #pragma unroll
  for (int r = tg; r < 16; r += 4)
    xs[r][c] = X[(t0 + r) * 64 + c];
  __syncthreads();
  float qa[4] = {0.f,0.f,0.f,0.f};
  float ka[4] = {0.f,0.f,0.f,0.f};
  float va[4] = {0.f,0.f,0.f,0.f};
  for (int j = 0; j < 64; ++j) {
    const float wq = WQ[j * 64 + c];
    const float wk = WK[j * 64 + c];
    const float wv = WV[j * 64 + c];
    #pragma unroll
    for (int r = 0; r < 4; ++r) {
      const float x = xs[tg * 4 + r][j];
      qa[r] = fmaf(x, wq, qa[r]);
      ka[r] = fmaf(x, wk, ka[r]);
      va[r] = fmaf(x, wv, va[r]);
    }
  }
  #pragma unroll
  for (int r = 0; r < 4; ++r) {
    const int t = tg * 4 + r;
    const size_t idx = (t0 + t) * 64 + c;
    Q[idx] = qa[r];
    unsigned short h, m, l;
    split3(ka[r], h, m, l);
    Kh[idx] = h; Km[idx] = m; Kl[idx] = l;
    split3(va[r], h, m, l);
    vs[0][t][c] = h; vs[1][t][c] = m; vs[2][t][c] = l;
  }
  __syncthreads();
  {
    const int row  = threadIdx.x >> 2;        // c: 0..63
    const int part = threadIdx.x & 3;         // 4-token group
    const size_t bofs = (t0 >> 10) * ((size_t)DIMN * 64);
    const size_t kt   = (t0 & 1023) >> 5;
    const size_t tin  = (t0 & 31) + part * 4;
    unsigned short* dst[3] = {VhT, VmT, VlT};
    #pragma unroll
    for (int term = 0; term < 3; ++term) {
      us4 pk;
      #pragma unroll
      for (int i = 0; i < 4; ++i) pk[i] = vs[term][part * 4 + i][row];
      *(us4*)&dst[term][bofs + kt * 2048 + (size_t)row * 32 + tin] = pk;
    }
  }
}

// ---------------------------------------------------------------------------
// 3) MFMA flash attention, 2-STRIP register blocking:
//    128-thread blocks (2 waves), each wave computes TWO 16-row strips, so
//    every K/V B-fragment read from LDS feeds 12 MFMAs instead of 6 —
//    halves the dominant LDS frag-read traffic per Q-row.
//    Per strip the arithmetic (split values, MFMA chain order, softmax order)
//    is EXACTLY r5's => bit-identical output (absmax 0.0).
//    LDS: K 13.8 + V^T 15.4 + P 4.6 = 33.8 KB -> 4 blocks/CU (8 waves/CU).
// ---------------------------------------------------------------------------
__global__ __launch_bounds__(128) void k_attn_s2(
    const float* __restrict__ Qg,
    const unsigned short* __restrict__ Kh, const unsigned short* __restrict__ Km,
    const unsigned short* __restrict__ Kl,
    const unsigned short* __restrict__ VhT, const unsigned short* __restrict__ VmT,
    const unsigned short* __restrict__ VlT,
    float* __restrict__ X, float* __restrict__ meanout) {
  __shared__ __align__(16) unsigned short Khs[32 * 72];
  __shared__ __align__(16) unsigned short Kms[32 * 72];
  __shared__ __align__(16) unsigned short Kls[32 * 72];
  __shared__ __align__(16) unsigned short Vhs[64 * 40];   // V^T: [c][j]
  __shared__ __align__(16) unsigned short Vms[64 * 40];
  __shared__ __align__(16) unsigned short Vls[64 * 40];
  __shared__ __align__(16) float Pb[32 * 36];             // fp32 P, per-wave rows

  const int tid  = threadIdx.x;           // 0..127
  const int w    = tid >> 6;              // wave 0..1
  const int lane = tid & 63;
  const int ln   = lane & 15;
  const int q    = lane >> 4;
  const int b    = blockIdx.y;
  const int i0   = blockIdx.x * 64;
  const size_t base = (size_t)b * (DIMN * 64);
  const float scale = 0.03125f;

  // ---- Q fragments for both strips: 3-term split, 2 k-chunks ---------------
  bf16x8 qh[2][2], qm[2][2], ql[2][2];    // [strip][k-chunk]
  #pragma unroll
  for (int p = 0; p < 2; ++p) {
    const int mrow = i0 + 32 * w + 16 * p + ln;
    const float* qp = Qg + base + (size_t)mrow * 64 + 8 * q;
    #pragma unroll
    for (int s = 0; s < 2; ++s) {
      const float4 x0 = ((const float4*)(qp + 32 * s))[0];
      const float4 x1 = ((const float4*)(qp + 32 * s))[1];
      const float xv[8] = {x0.x, x0.y, x0.z, x0.w, x1.x, x1.y, x1.z, x1.w};
      union { bf16x8 v; unsigned short e[8]; } uh, um, ul;
      #pragma unroll
      for (int j = 0; j < 8; ++j) {
        unsigned short h, m, l;
        split3(xv[j], h, m, l);
        uh.e[j] = h; um.e[j] = m; ul.e[j] = l;
      }
      qh[p][s] = uh.v; qm[p][s] = um.v; ql[p][s] = ul.v;
    }
  }

  f32x4 O[2][4];
  float m_run[2][4], l_run[2][4];
  #pragma unroll
  for (int p = 0; p < 2; ++p) {
    #pragma unroll
    for (int ct = 0; ct < 4; ++ct) O[p][ct] = (f32x4){0.f, 0.f, 0.f, 0.f};
    #pragma unroll
    for (int r = 0; r < 4; ++r) { m_run[p][r] = -INFINITY; l_run[p][r] = 0.f; }
  }

  for (int kt = 0; kt < 32; ++kt) {
    __syncthreads();   // previous iteration's K/V readers done

    // ---- stage pre-split K/V tile: pure 16B copies, 2 chunks/thread --------
    #pragma unroll
    for (int c = 0; c < 2; ++c) {
      const int tt = 128 * c + tid;       // 0..255
      const size_t tof = base + (size_t)kt * 2048 + (size_t)tt * 8;
      const int klo = (tt >> 3) * 72 + (tt & 7) * 8;
      const int vlo = (tt >> 2) * 40 + (tt & 3) * 8;
      const us8 a0 = *(const us8*)&Kh[tof];
      const us8 a1 = *(const us8*)&Km[tof];
      const us8 a2 = *(const us8*)&Kl[tof];
      const us8 b0 = *(const us8*)&VhT[tof];
      const us8 b1 = *(const us8*)&VmT[tof];
      const us8 b2 = *(const us8*)&VlT[tof];
      *(us8*)&Khs[klo] = a0;
      *(us8*)&Kms[klo] = a1;
      *(us8*)&Kls[klo] = a2;
      *(us8*)&Vhs[vlo] = b0;
      *(us8*)&Vms[vlo] = b1;
      *(us8*)&Vls[vlo] = b2;
    }
    __syncthreads();

    // ---- S strips: load each K frag once, feed BOTH strips -----------------
    f32x4 sacc[2][2];                     // [strip][ct]
    #pragma unroll
    for (int p = 0; p < 2; ++p)
      #pragma unroll
      for (int ct = 0; ct < 2; ++ct)
        sacc[p][ct] = (f32x4){0.f, 0.f, 0.f, 0.f};
    #pragma unroll
    for (int ct = 0; ct < 2; ++ct) {
      #pragma unroll
      for (int s = 0; s < 2; ++s) {
        const int ko = (16 * ct + ln) * 72 + 32 * s + 8 * q;
        const bf16x8 bh = ld16B(&Khs[ko]);
        const bf16x8 bm = ld16B(&Kms[ko]);
        const bf16x8 bl = ld16B(&Kls[ko]);
        #pragma unroll
        for (int p = 0; p < 2; ++p) {
          f32x4 a = sacc[p][ct];
          a = MFMA16(ql[p][s], bh, a);    // same order as r5 per strip
          a = MFMA16(qh[p][s], bl, a);
          a = MFMA16(qm[p][s], bm, a);
          a = MFMA16(qm[p][s], bh, a);
          a = MFMA16(qh[p][s], bm, a);
          a = MFMA16(qh[p][s], bh, a);
          sacc[p][ct] = a;
        }
      }
    }

    // ---- per-strip wave-local online softmax + P split (r5-identical) ------
    bf16x8 ph[2], pm[2], pl[2];
    #pragma unroll
    for (int p = 0; p < 2; ++p) {
      float rmax[4];
      #pragma unroll
      for (int r = 0; r < 4; ++r)
        rmax[r] = fmaxf(sacc[p][0][r], sacc[p][1][r]);
      #pragma unroll
      for (int mk = 1; mk <= 8; mk <<= 1) {
        #pragma unroll
        for (int r = 0; r < 4; ++r)
          rmax[r] = fmaxf(rmax[r], __shfl_xor(rmax[r], mk, 64));
      }
      float alpha[4], rsum[4];
      #pragma unroll
      for (int r = 0; r < 4; ++r) {
        const float mnew = fmaxf(m_run[p][r], rmax[r] * scale);
        alpha[r] = __expf(m_run[p][r] - mnew);
        m_run[p][r] = mnew;
        rsum[r] = 0.f;
      }
      #pragma unroll
      for (int ct = 0; ct < 2; ++ct) {
        #pragma unroll
        for (int r = 0; r < 4; ++r) {
          const float pv = __expf(sacc[p][ct][r] * scale - m_run[p][r]);
          rsum[r] += pv;
          Pb[(16 * w + 4 * q + r) * 36 + ln + 16 * ct] = pv;   // fp32
        }
      }
      #pragma unroll
      for (int mk = 1; mk <= 8; mk <<= 1) {
        #pragma unroll
        for (int r = 0; r < 4; ++r)
          rsum[r] += __shfl_xor(rsum[r], mk, 64);
      }
      #pragma unroll
      for (int r = 0; r < 4; ++r)
        l_run[p][r] = l_run[p][r] * alpha[r] + rsum[r];

      #pragma unroll
      for (int ct = 0; ct < 4; ++ct) {
        #pragma unroll
        for (int r = 0; r < 4; ++r) O[p][ct][r] *= alpha[r];
      }

      // P A-fragment: own rows, fp32 -> 3-term split (wave-local round trip;
      // same-wave LDS ordering makes this safe without a barrier)
      {
        const float* pp = &Pb[(16 * w + ln) * 36 + 8 * q];
        const float4 p0 = ((const float4*)pp)[0];
        const float4 p1 = ((const float4*)pp)[1];
        const float pvv[8] = {p0.x, p0.y, p0.z, p0.w, p1.x, p1.y, p1.z, p1.w};
        union { bf16x8 v; unsigned short e[8]; } uh, um, ul;
        #pragma unroll
        for (int j = 0; j < 8; ++j) {
          unsigned short h, m, l;
          split3(pvv[j], h, m, l);
          uh.e[j] = h; um.e[j] = m; ul.e[j] = l;
        }
        ph[p] = uh.v; pm[p] = um.v; pl[p] = ul.v;
      }
    }

    // ---- O += P @ V: load each V frag once, feed BOTH strips ---------------
    #pragma unroll
    for (int ct = 0; ct < 4; ++ct) {
      const int vo = (16 * ct + ln) * 40 + 8 * q;
      const bf16x8 vvh = ld16B(&Vhs[vo]);
      const bf16x8 vvm = ld16B(&Vms[vo]);
      const bf16x8 vvl = ld16B(&Vls[vo]);
      #pragma unroll
      for (int p = 0; p < 2; ++p) {
        f32x4 o = O[p][ct];
        o = MFMA16(ph[p], vvh, o);        // same order as r5 per strip
        o = MFMA16(ph[p], vvm, o);
        o = MFMA16(pm[p], vvh, o);
        o = MFMA16(pm[p], vvm, o);
        o = MFMA16(ph[p], vvl, o);
        o = MFMA16(pl[p], vvh, o);
        O[p][ct] = o;
      }
    }
  }

  // ---- epilogue: X += O/l per strip; fused channel-mean on last layer ------
  #pragma unroll
  for (int p = 0; p < 2; ++p) {
    float linv[4];
    #pragma unroll
    for (int r = 0; r < 4; ++r) linv[r] = 1.0f / l_run[p][r];
    #pragma unroll
    for (int r = 0; r < 4; ++r) {
      const int row = i0 + 32 * w + 16 * p + 4 * q + r;
      float srow = 0.f;
      #pragma unroll
      for (int ct = 0; ct < 4; ++ct) {
        float* xp = X + base + (size_t)row * 64 + ln + 16 * ct;
        const float nv = *xp + O[p][ct][r] * linv[r];
        *xp = nv;
        srow += nv;
      }
      if (meanout) {
        #pragma unroll
        for (int mk = 1; mk <= 8; mk <<= 1)
          srow += __shfl_xor(srow, mk, 64);
        if (ln == 0) meanout[(size_t)b * DIMN + row] = srow * (1.0f / 64.0f);
      }
    }
  }
}

// ---------------------------------------------------------------------------
// 4) head stage 2: pred[b,k] = meanv[b,:] . last_W[k,:] + last_b[k]
// ---------------------------------------------------------------------------
__global__ __launch_bounds__(256) void k_head2(
    const float* __restrict__ meanv, const float* __restrict__ lW,
    const float* __restrict__ lb, float* __restrict__ out) {
  __shared__ float red[256];
  const int b   = blockIdx.x;
  const int tid = threadIdx.x;
  float acc[NCLS];
  #pragma unroll
  for (int k = 0; k < NCLS; ++k) acc[k] = 0.f;
  for (int n = tid; n < DIMN; n += 256) {
    const float m = meanv[(size_t)b * DIMN + n];
    #pragma unroll
    for (int k = 0; k < NCLS; ++k)
      acc[k] = fmaf(m, lW[k * DIMN + n], acc[k]);
  }
  for (int k = 0; k < NCLS; ++k) {
    red[tid] = acc[k];
    __syncthreads();
    for (int s = 128; s > 0; s >>= 1) {
      if (tid < s) red[tid] += red[tid + s];
      __syncthreads();
    }
    if (tid == 0) out[b * NCLS + k] = red[0] + lb[k];
    __syncthreads();
  }
}

// ===========================================================================
// FALLBACK PATH (round-3 kernels, ws too small): proven absmax 0.0
// ===========================================================================
__global__ __launch_bounds__(256) void k_qkv(
    const float* __restrict__ X,
    const float* __restrict__ WQ, const float* __restrict__ WK,
    const float* __restrict__ WV,
    float* __restrict__ Q, float* __restrict__ K, float* __restrict__ V) {
  __shared__ float xs[16][64];
  const int c  = threadIdx.x & 63;
  const int tg = threadIdx.x >> 6;
  const size_t t0 = (size_t)blockIdx.x * 16;
  #pragma unroll
  for (int r = tg; r < 16; r += 4)
    xs[r][c] = X[(t0 + r) * 64 + c];
  __syncthreads();
  float qa[4] = {0.f,0.f,0.f,0.f};
  float ka[4] = {0.f,0.f,0.f,0.f};
  float va[4] = {0.f,0.f,0.f,0.f};
  for (int j = 0; j < 64; ++j) {
    const float wq = WQ[j * 64 + c];
    const float wk = WK[j * 64 + c];
    const float wv = WV[j * 64 + c];
    #pragma unroll
    for (int r = 0; r < 4; ++r) {
      const float x = xs[tg * 4 + r][j];
      qa[r] = fmaf(x, wq, qa[r]);
      ka[r] = fmaf(x, wk, ka[r]);
      va[r] = fmaf(x, wv, va[r]);
    }
  }
  #pragma unroll
  for (int r = 0; r < 4; ++r) {
    const size_t idx = (t0 + tg * 4 + r) * 64 + c;
    Q[idx] = qa[r]; K[idx] = ka[r]; V[idx] = va[r];
  }
}

__global__ __launch_bounds__(256) void k_attn_mfma(
    const float* __restrict__ Qg, const float* __restrict__ Kg,
    const float* __restrict__ Vg, float* __restrict__ X) {
  __shared__ __align__(16) unsigned short Kh[32 * 72];
  __shared__ __align__(16) unsigned short Km[32 * 72];
  __shared__ __align__(16) unsigned short Kl[32 * 72];
  __shared__ __align__(16) unsigned short Vh[64 * 40];
  __shared__ __align__(16) unsigned short Vm[64 * 40];
  __shared__ __align__(16) unsigned short Vl[64 * 40];
  __shared__ __align__(16) float Pb[64 * 36];

  const int tid  = threadIdx.x;
  const int w    = tid >> 6;
  const int lane = tid & 63;
  const int ln   = lane & 15;
  const int q    = lane >> 4;
  const int b    = blockIdx.y;
  const int i0   = blockIdx.x * 64;
  const size_t base = (size_t)b * (DIMN * 64);
  const float scale = 0.03125f;

  const float* Kbase = Kg + base;
  const float* Vbase = Vg + base;

  bf16x8 qh[2], qm[2], ql[2];
  {
    const int mrow = i0 + 16 * w + ln;
    const float* qp = Qg + base + (size_t)mrow * 64 + 8 * q;
    #pragma unroll
    for (int s = 0; s < 2; ++s) {
      const float4 x0 = ((const float4*)(qp + 32 * s))[0];
      const float4 x1 = ((const float4*)(qp + 32 * s))[1];
      const float xv[8] = {x0.x, x0.y, x0.z, x0.w, x1.x, x1.y, x1.z, x1.w};
      union { bf16x8 v; unsigned short e[8]; } uh, um, ul;
      #pragma unroll
      for (int j = 0; j < 8; ++j) {
        unsigned short h, m, l;
        split3(xv[j], h, m, l);
        uh.e[j] = h; um.e[j] = m; ul.e[j] = l;
      }
      qh[s] = uh.v; qm[s] = um.v; ql[s] = ul.v;
    }
  }

  f32x4 O[4];
  #pragma unroll
  for (int ct = 0; ct < 4; ++ct) O[ct] = (f32x4){0.f, 0.f, 0.f, 0.f};
  float m_run[4] = {-INFINITY, -INFINITY, -INFINITY, -INFINITY};
  float l_run[4] = {0.f, 0.f, 0.f, 0.f};

  for (int kt = 0; kt < 32; ++kt) {
    __syncthreads();
    {
      const int j  = tid >> 3;
      const int dq = tid & 7;
      const float* kp = Kbase + (size_t)(kt * 32 + j) * 64 + 8 * dq;
      const float4 a0 = ((const float4*)kp)[0];
      const float4 a1 = ((const float4*)kp)[1];
      const float xv[8] = {a0.x, a0.y, a0.z, a0.w, a1.x, a1.y, a1.z, a1.w};
      const int o = j * 72 + 8 * dq;
      us4 hh[2], mm[2], llv[2];
      #pragma unroll
      for (int e = 0; e < 8; ++e) {
        unsigned short h, m, l;
        split3(xv[e], h, m, l);
        hh[e >> 2][e & 3] = h; mm[e >> 2][e & 3] = m; llv[e >> 2][e & 3] = l;
      }
      *(us4*)&Kh[o] = hh[0];  *(us4*)&Kh[o + 4] = hh[1];
      *(us4*)&Km[o] = mm[0];  *(us4*)&Km[o + 4] = mm[1];
      *(us4*)&Kl[o] = llv[0]; *(us4*)&Kl[o + 4] = llv[1];
    }
    {
      const int jp = tid >> 4;
      const int cq = tid & 15;
      const float* vp = Vbase + (size_t)(kt * 32 + 2 * jp) * 64 + 4 * cq;
      const float4 a = *(const float4*)vp;
      const float4 bb = *(const float4*)(vp + 64);
      const float av[4] = {a.x, a.y, a.z, a.w};
      const float bv[4] = {bb.x, bb.y, bb.z, bb.w};
      #pragma unroll
      for (int e = 0; e < 4; ++e) {
        const int c = 4 * cq + e;
        unsigned short h1, m1, l1, h2, m2, l2;
        split3(av[e], h1, m1, l1);
        split3(bv[e], h2, m2, l2);
        *(unsigned int*)&Vh[c * 40 + 2 * jp] = (unsigned)h1 | ((unsigned)h2 << 16);
        *(unsigned int*)&Vm[c * 40 + 2 * jp] = (unsigned)m1 | ((unsigned)m2 << 16);
        *(unsigned int*)&Vl[c * 40 + 2 * jp] = (unsigned)l1 | ((unsigned)l2 << 16);
      }
    }
    __syncthreads();

    f32x4 sacc[2];
    #pragma unroll
    for (int ct = 0; ct < 2; ++ct) {
      f32x4 a = (f32x4){0.f, 0.f, 0.f, 0.f};
      #pragma unroll
      for (int s = 0; s < 2; ++s) {
        const int ko = (16 * ct + ln) * 72 + 32 * s + 8 * q;
        const bf16x8 bh = ld16B(&Kh[ko]);
        const bf16x8 bm = ld16B(&Km[ko]);
        const bf16x8 bl = ld16B(&Kl[ko]);
        a = MFMA16(ql[s], bh, a);
        a = MFMA16(qh[s], bl, a);
        a = MFMA16(qm[s], bm, a);
        a = MFMA16(qm[s], bh, a);
        a = MFMA16(qh[s], bm, a);
        a = MFMA16(qh[s], bh, a);
      }
      sacc[ct] = a;
    }

    float rmax[4];
    #pragma unroll
    for (int r = 0; r < 4; ++r)
      rmax[r] = fmaxf(sacc[0][r], sacc[1][r]);
    #pragma unroll
    for (int mk = 1; mk <= 8; mk <<= 1) {
      #pragma unroll
      for (int r = 0; r < 4; ++r)
        rmax[r] = fmaxf(rmax[r], __shfl_xor(rmax[r], mk, 64));
    }
    float alpha[4], rsum[4];
    #pragma unroll
    for (int r = 0; r < 4; ++r) {
      const float mnew = fmaxf(m_run[r], rmax[r] * scale);
      alpha[r] = __expf(m_run[r] - mnew);
      m_run[r] = mnew;
      rsum[r] = 0.f;
    }
    #pragma unroll
    for (int ct = 0; ct < 2; ++ct) {
      #pragma unroll
      for (int r = 0; r < 4; ++r) {
        const float pv = __expf(sacc[ct][r] * scale - m_run[r]);
        rsum[r] += pv;
        Pb[(16 * w + 4 * q + r) * 36 + ln + 16 * ct] = pv;
      }
    }
    #pragma unroll
    for (int mk = 1; mk <= 8; mk <<= 1) {
      #pragma unroll
      for (int r = 0; r < 4; ++r)
        rsum[r] += __shfl_xor(rsum[r], mk, 64);
    }
    #pragma unroll
    for (int r = 0; r < 4; ++r)
      l_run[r] = l_run[r] * alpha[r] + rsum[r];

    #pragma unroll
    for (int ct = 0; ct < 4; ++ct) {
      #pragma unroll
      for (int r = 0; r < 4; ++r) O[ct][r] *= alpha[r];
    }

    bf16x8 ph, pm, pl;
    {
      const float* pp = &Pb[(16 * w + ln) * 36 + 8 * q];
      const float4 p0 = ((const float4*)pp)[0];
      const float4 p1 = ((const float4*)pp)[1];
      const float pvv[8] = {p0.x, p0.y, p0.z, p0.w, p1.x, p1.y, p1.z, p1.w};
      union { bf16x8 v; unsigned short e[8]; } uh, um, ul;
      #pragma unroll
      for (int j = 0; j < 8; ++j) {
        unsigned short h, m, l;
        split3(pvv[j], h, m, l);
        uh.e[j] = h; um.e[j] = m; ul.e[j] = l;
      }
      ph = uh.v; pm = um.v; pl = ul.v;
    }

    #pragma unroll
    for (int ct = 0; ct < 4; ++ct) {
      const int vo = (16 * ct + ln) * 40 + 8 * q;
      const bf16x8 vvh = ld16B(&Vh[vo]);
      const bf16x8 vvm = ld16B(&Vm[vo]);
      const bf16x8 vvl = ld16B(&Vl[vo]);
      O[ct] = MFMA16(ph, vvh, O[ct]);
      O[ct] = MFMA16(ph, vvm, O[ct]);
      O[ct] = MFMA16(pm, vvh, O[ct]);
      O[ct] = MFMA16(pm, vvm, O[ct]);
      O[ct] = MFMA16(ph, vvl, O[ct]);
      O[ct] = MFMA16(pl, vvh, O[ct]);
    }
  }

  float linv[4];
  #pragma unroll
  for (int r = 0; r < 4; ++r) linv[r] = 1.0f / l_run[r];
  #pragma unroll
  for (int ct = 0; ct < 4; ++ct) {
    #pragma unroll
    for (int r = 0; r < 4; ++r) {
      float* xp = X + base + (size_t)(i0 + 16 * w + 4 * q + r) * 64 + ln + 16 * ct;
      *xp += O[ct][r] * linv[r];
    }
  }
}

__global__ __launch_bounds__(256) void k_head(
    const float* __restrict__ X, const float* __restrict__ lW,
    const float* __restrict__ lb, float* __restrict__ out) {
  __shared__ float meanv[DIMN];
  __shared__ float red[256];
  const int b    = blockIdx.x;
  const int tid  = threadIdx.x;
  const int lane = tid & 63;
  const int w    = tid >> 6;
  const float* Xb = X + (size_t)b * DIMN * 64;
  for (int n = w; n < DIMN; n += 4) {
    float v = Xb[(size_t)n * 64 + lane];
    #pragma unroll
    for (int off = 32; off > 0; off >>= 1)
      v += __shfl_down(v, off, 64);
    if (lane == 0) meanv[n] = v * (1.0f / 64.0f);
  }
  __syncthreads();
  float acc[NCLS];
  #pragma unroll
  for (int k = 0; k < NCLS; ++k) acc[k] = 0.f;
  for (int n = tid; n < DIMN; n += 256) {
    const float m = meanv[n];
    #pragma unroll
    for (int k = 0; k < NCLS; ++k)
      acc[k] = fmaf(m, lW[k * DIMN + n], acc[k]);
  }
  for (int k = 0; k < NCLS; ++k) {
    red[tid] = acc[k];
    __syncthreads();
    for (int s = 128; s > 0; s >>= 1) {
      if (tid < s) red[tid] += red[tid + s];
      __syncthreads();
    }
    if (tid == 0) out[b * NCLS + k] = red[0] + lb[k];
    __syncthreads();
  }
}

// ---------------------------------------------------------------------------
// launch
// ---------------------------------------------------------------------------
extern "C" void kernel_launch(void* const* d_in, const int* in_sizes, int n_in,
                              void* d_out, int out_size, void* d_ws, size_t ws_size,
                              hipStream_t stream) {
  const float* image = (const float*)d_in[0];
  const float* WV    = (const float*)d_in[1];
  const float* WK    = (const float*)d_in[2];
  const float* WQ    = (const float*)d_in[3];
  const float* lW    = (const float*)d_in[4];
  const float* lb    = (const float*)d_in[5];
  float* out = (float*)d_out;

  float* ws = (float*)d_ws;
  const size_t NELEM = (size_t)BB * DIMN * CCH;   // 2,097,152

  const size_t need_fast = 2 * NELEM * sizeof(float)          // X, Q
                         + 6 * NELEM * sizeof(unsigned short) // K/V splits
                         + (size_t)BB * DIMN * sizeof(float); // meanv

  if (ws_size >= need_fast) {
    float* X = ws;
    float* Q = ws + NELEM;
    unsigned short* Kh  = (unsigned short*)(ws + 2 * NELEM);
    unsigned short* Km  = Kh + NELEM;
    unsigned short* Kl  = Kh + 2 * NELEM;
    unsigned short* VhT = Kh + 3 * NELEM;
    unsigned short* VmT = Kh + 4 * NELEM;
    unsigned short* VlT = Kh + 5 * NELEM;
    float* meanv = (float*)(Kh + 6 * NELEM);

    k_transpose<<<dim3(DIMN / 64, BB), 256, 0, stream>>>(image, X);
    for (int layer = 0; layer < 8; ++layer) {
      k_qkv_split<<<(BB * DIMN) / 16, 256, 0, stream>>>(
          X, WQ, WK, WV, Q, Kh, Km, Kl, VhT, VmT, VlT);
      k_attn_s2<<<dim3(DIMN / 64, BB), 128, 0, stream>>>(
          Q, Kh, Km, Kl, VhT, VmT, VlT, X, (layer == 7) ? meanv : nullptr);
    }
    k_head2<<<BB, 256, 0, stream>>>(meanv, lW, lb, out);
  } else {
    float* X = ws;
    float* Q = ws + NELEM;
    float* K = ws + 2 * NELEM;
    float* V = ws + 3 * NELEM;
    k_transpose<<<dim3(DIMN / 64, BB), 256, 0, stream>>>(image, X);
    for (int layer = 0; layer < 8; ++layer) {
      k_qkv<<<(BB * DIMN) / 16, 256, 0, stream>>>(X, WQ, WK, WV, Q, K, V);
      k_attn_mfma<<<dim3(DIMN / 64, BB), 256, 0, stream>>>(Q, K, V, X);
    }
    k_head<<<BB, 256, 0, stream>>>(X, lW, lb, out);
  }
}

// Round 7
// 981.395 us; speedup vs baseline: 1.4508x; 1.4508x over previous
//
#include <hip/hip_runtime.h>
#include <math.h>

#define BB    32
#define CCH   64
#define DIMN  1024
#define NCLS  10

typedef __attribute__((ext_vector_type(8))) short bf16x8;
typedef __attribute__((ext_vector_type(4))) float f32x4;
typedef __attribute__((ext_vector_type(4))) unsigned short us4;
typedef __attribute__((ext_vector_type(8))) unsigned short us8;

#define MFMA16(a, b, c) __builtin_amdgcn_mfma_f32_16x16x32_bf16(a, b, c, 0, 0, 0)

__device__ __forceinline__ unsigned short f2bf(float x) {
  unsigned u = __float_as_uint(x);
  unsigned r = u + 0x7fffu + ((u >> 16) & 1u);   // round-to-nearest-even
  return (unsigned short)(r >> 16);
}
__device__ __forceinline__ float bf2f(unsigned short h) {
  return __uint_as_float(((unsigned)h) << 16);
}
// x == h + m + l to ~2^-26 relative
__device__ __forceinline__ void split3(float x, unsigned short& h,
                                       unsigned short& m, unsigned short& l) {
  h = f2bf(x); float hf = bf2f(h);
  float r = x - hf;
  m = f2bf(r); float mf = bf2f(m);
  l = f2bf(r - mf);
}
__device__ __forceinline__ bf16x8 ld16B(const unsigned short* p) {
  union { us8 u; bf16x8 v; } c;
  c.u = *(const us8*)p;           // 16B-aligned -> ds_read_b128
  return c.v;
}

// ---------------------------------------------------------------------------
// 1) transpose: image (B,C,DIM) -> X (B,DIM,C)
// ---------------------------------------------------------------------------
__global__ __launch_bounds__(256) void k_transpose(const float* __restrict__ img,
                                                   float* __restrict__ X) {
  __shared__ float tile[64][65];
  const int b  = blockIdx.y;
  const int n0 = blockIdx.x * 64;
  const int tx = threadIdx.x & 63;
  const int ty = threadIdx.x >> 6;
  const float* src = img + (size_t)b * CCH * DIMN;
  #pragma unroll
  for (int c = ty; c < 64; c += 4)
    tile[c][tx] = src[(size_t)c * DIMN + n0 + tx];
  __syncthreads();
  float* dst = X + (size_t)b * DIMN * CCH;
  #pragma unroll
  for (int nn = ty; nn < 64; nn += 4)
    dst[(size_t)(n0 + nn) * CCH + tx] = tile[tx][nn];
}

// ---------------------------------------------------------------------------
// 2) QKV + per-layer pre-split (unchanged from r5: proven absmax 0.0):
//    Q fp32; K 3-term bf16 [t][c]; V 3-term bf16 transposed+tiled [b][kt][c][32]
// ---------------------------------------------------------------------------
__global__ __launch_bounds__(256) void k_qkv_split(
    const float* __restrict__ X,
    const float* __restrict__ WQ, const float* __restrict__ WK,
    const float* __restrict__ WV,
    float* __restrict__ Q,
    unsigned short* __restrict__ Kh, unsigned short* __restrict__ Km,
    unsigned short* __restrict__ Kl,
    unsigned short* __restrict__ VhT, unsigned short* __restrict__ VmT,
    unsigned short* __restrict__ VlT) {
  __shared__ float xs[16][64];
  __shared__ unsigned short vs[3][16][64];
  const int c  = threadIdx.x & 63;
  const int tg = threadIdx.x >> 6;
  const size_t t0 = (size_t)blockIdx.x * 16;
  #pragma unroll
  for (int r = tg; r < 16; r += 4)
    xs[r][c] = X[(t0 + r) * 64 + c];
  __syncthreads();
  float qa[4] = {0.f,0.f,0.f,0.f};
  float ka[4] = {0.f,0.f,0.f,0.f};
  float va[4] = {0.f,0.f,0.f,0.f};
  for (int j = 0; j < 64; ++j) {
    const float wq = WQ[j * 64 + c];
    const float wk = WK[j * 64 + c];
    const float wv = WV[j * 64 + c];
    #pragma unroll
    for (int r = 0; r < 4; ++r) {
      const float x = xs[tg * 4 + r][j];
      qa[r] = fmaf(x, wq, qa[r]);
      ka[r] = fmaf(x, wk, ka[r]);
      va[r] = fmaf(x, wv, va[r]);
    }
  }
  #pragma unroll
  for (int r = 0; r < 4; ++r) {
    const int t = tg * 4 + r;
    const size_t idx = (t0 + t) * 64 + c;
    Q[idx] = qa[r];
    unsigned short h, m, l;
    split3(ka[r], h, m, l);
    Kh[idx] = h; Km[idx] = m; Kl[idx] = l;
    split3(va[r], h, m, l);
    vs[0][t][c] = h; vs[1][t][c] = m; vs[2][t][c] = l;
  }
  __syncthreads();
  {
    const int row  = threadIdx.x >> 2;        // c: 0..63
    const int part = threadIdx.x & 3;         // 4-token group
    const size_t bofs = (t0 >> 10) * ((size_t)DIMN * 64);
    const size_t kt   = (t0 & 1023) >> 5;
    const size_t tin  = (t0 & 31) + part * 4;
    unsigned short* dst[3] = {VhT, VmT, VlT};
    #pragma unroll
    for (int term = 0; term < 3; ++term) {
      us4 pk;
      #pragma unroll
      for (int i = 0; i < 4; ++i) pk[i] = vs[term][part * 4 + i][row];
      *(us4*)&dst[term][bofs + kt * 2048 + (size_t)row * 32 + tin] = pk;
    }
  }
}

// ---------------------------------------------------------------------------
// 3) MFMA flash attention, CONCURRENCY-MAX config:
//    32-row Q tiles, 128-thread blocks (2 waves, one 16-row strip each),
//    grid (32,32)=1024 blocks -> 4 blocks/CU x 2 waves = 8 waves/CU with
//    barriers covering only 2 waves, staggered across 4 independent blocks
//    (r6 lesson: the kernel is latency/barrier-bound, not LDS-throughput-bound).
//    + register-prefetch double buffering: tile kt+1 is loaded global->regs
//    during compute of kt; the ds_write next iter absorbs the vmcnt wait.
//    Per-strip arithmetic EXACTLY r5's => bit-identical output (absmax 0.0).
//    LDS: K 13.8 + V^T 15.4 + P 4.6 = 33.8 KB -> 4 blocks/CU fits (135 KB).
// ---------------------------------------------------------------------------
__global__ __launch_bounds__(128) void k_attn_s3(
    const float* __restrict__ Qg,
    const unsigned short* __restrict__ Kh, const unsigned short* __restrict__ Km,
    const unsigned short* __restrict__ Kl,
    const unsigned short* __restrict__ VhT, const unsigned short* __restrict__ VmT,
    const unsigned short* __restrict__ VlT,
    float* __restrict__ X, float* __restrict__ meanout) {
  __shared__ __align__(16) unsigned short Khs[32 * 72];
  __shared__ __align__(16) unsigned short Kms[32 * 72];
  __shared__ __align__(16) unsigned short Kls[32 * 72];
  __shared__ __align__(16) unsigned short Vhs[64 * 40];   // V^T: [c][j]
  __shared__ __align__(16) unsigned short Vms[64 * 40];
  __shared__ __align__(16) unsigned short Vls[64 * 40];
  __shared__ __align__(16) float Pb[32 * 36];             // fp32 P, 2 waves

  const int tid  = threadIdx.x;           // 0..127
  const int w    = tid >> 6;              // wave 0..1
  const int lane = tid & 63;
  const int ln   = lane & 15;
  const int q    = lane >> 4;
  const int b    = blockIdx.y;
  const int i0   = blockIdx.x * 32;
  const size_t base = (size_t)b * (DIMN * 64);
  const float scale = 0.03125f;

  // LDS staging destinations for this thread's two 16B chunks
  int klo[2], vlo[2];
  #pragma unroll
  for (int c = 0; c < 2; ++c) {
    const int tt = 128 * c + tid;         // 0..255
    klo[c] = (tt >> 3) * 72 + (tt & 7) * 8;
    vlo[c] = (tt >> 2) * 40 + (tt & 3) * 8;
  }

  // ---- Q fragments: 3-term split, 2 k-chunks (once per block) --------------
  bf16x8 qh[2], qm[2], ql[2];
  {
    const int mrow = i0 + 16 * w + ln;
    const float* qp = Qg + base + (size_t)mrow * 64 + 8 * q;
    #pragma unroll
    for (int s = 0; s < 2; ++s) {
      const float4 x0 = ((const float4*)(qp + 32 * s))[0];
      const float4 x1 = ((const float4*)(qp + 32 * s))[1];
      const float xv[8] = {x0.x, x0.y, x0.z, x0.w, x1.x, x1.y, x1.z, x1.w};
      union { bf16x8 v; unsigned short e[8]; } uh, um, ul;
      #pragma unroll
      for (int j = 0; j < 8; ++j) {
        unsigned short h, m, l;
        split3(xv[j], h, m, l);
        uh.e[j] = h; um.e[j] = m; ul.e[j] = l;
      }
      qh[s] = uh.v; qm[s] = um.v; ql[s] = ul.v;
    }
  }

  f32x4 O[4];
  #pragma unroll
  for (int ct = 0; ct < 4; ++ct) O[ct] = (f32x4){0.f, 0.f, 0.f, 0.f};
  float m_run[4] = {-INFINITY, -INFINITY, -INFINITY, -INFINITY};
  float l_run[4] = {0.f, 0.f, 0.f, 0.f};

  // ---- prefetch tile 0 into registers --------------------------------------
  us8 pf[6][2];
  #pragma unroll
  for (int c = 0; c < 2; ++c) {
    const size_t tof = base + (size_t)(128 * c + tid) * 8;
    pf[0][c] = *(const us8*)&Kh[tof];
    pf[1][c] = *(const us8*)&Km[tof];
    pf[2][c] = *(const us8*)&Kl[tof];
    pf[3][c] = *(const us8*)&VhT[tof];
    pf[4][c] = *(const us8*)&VmT[tof];
    pf[5][c] = *(const us8*)&VlT[tof];
  }

  for (int kt = 0; kt < 32; ++kt) {
    __syncthreads();   // previous iteration's K/V readers done

    // ---- commit prefetched tile to LDS (vmcnt wait lands here) -------------
    #pragma unroll
    for (int c = 0; c < 2; ++c) {
      *(us8*)&Khs[klo[c]] = pf[0][c];
      *(us8*)&Kms[klo[c]] = pf[1][c];
      *(us8*)&Kls[klo[c]] = pf[2][c];
      *(us8*)&Vhs[vlo[c]] = pf[3][c];
      *(us8*)&Vms[vlo[c]] = pf[4][c];
      *(us8*)&Vls[vlo[c]] = pf[5][c];
    }
    __syncthreads();

    // ---- issue next tile's global loads (latency hidden behind compute) ----
    if (kt + 1 < 32) {
      #pragma unroll
      for (int c = 0; c < 2; ++c) {
        const size_t tof = base + (size_t)(kt + 1) * 2048 + (size_t)(128 * c + tid) * 8;
        pf[0][c] = *(const us8*)&Kh[tof];
        pf[1][c] = *(const us8*)&Km[tof];
        pf[2][c] = *(const us8*)&Kl[tof];
        pf[3][c] = *(const us8*)&VhT[tof];
        pf[4][c] = *(const us8*)&VmT[tof];
        pf[5][c] = *(const us8*)&VlT[tof];
      }
    }

    // ---- S strip = Q . K^T via 6-product compensated MFMA (r5 order) -------
    f32x4 sacc[2];
    #pragma unroll
    for (int ct = 0; ct < 2; ++ct) {
      f32x4 a = (f32x4){0.f, 0.f, 0.f, 0.f};
      #pragma unroll
      for (int s = 0; s < 2; ++s) {
        const int ko = (16 * ct + ln) * 72 + 32 * s + 8 * q;
        const bf16x8 bh = ld16B(&Khs[ko]);
        const bf16x8 bm = ld16B(&Kms[ko]);
        const bf16x8 bl = ld16B(&Kls[ko]);
        a = MFMA16(ql[s], bh, a);
        a = MFMA16(qh[s], bl, a);
        a = MFMA16(qm[s], bm, a);
        a = MFMA16(qm[s], bh, a);
        a = MFMA16(qh[s], bm, a);
        a = MFMA16(qh[s], bh, a);
      }
      sacc[ct] = a;
    }

    // ---- wave-local online softmax (r5-identical) --------------------------
    float rmax[4];
    #pragma unroll
    for (int r = 0; r < 4; ++r)
      rmax[r] = fmaxf(sacc[0][r], sacc[1][r]);
    #pragma unroll
    for (int mk = 1; mk <= 8; mk <<= 1) {
      #pragma unroll
      for (int r = 0; r < 4; ++r)
        rmax[r] = fmaxf(rmax[r], __shfl_xor(rmax[r], mk, 64));
    }
    float alpha[4], rsum[4];
    #pragma unroll
    for (int r = 0; r < 4; ++r) {
      const float mnew = fmaxf(m_run[r], rmax[r] * scale);
      alpha[r] = __expf(m_run[r] - mnew);
      m_run[r] = mnew;
      rsum[r] = 0.f;
    }
    #pragma unroll
    for (int ct = 0; ct < 2; ++ct) {
      #pragma unroll
      for (int r = 0; r < 4; ++r) {
        const float pv = __expf(sacc[ct][r] * scale - m_run[r]);
        rsum[r] += pv;
        Pb[(16 * w + 4 * q + r) * 36 + ln + 16 * ct] = pv;   // fp32, wave-local
      }
    }
    #pragma unroll
    for (int mk = 1; mk <= 8; mk <<= 1) {
      #pragma unroll
      for (int r = 0; r < 4; ++r)
        rsum[r] += __shfl_xor(rsum[r], mk, 64);
    }
    #pragma unroll
    for (int r = 0; r < 4; ++r)
      l_run[r] = l_run[r] * alpha[r] + rsum[r];

    #pragma unroll
    for (int ct = 0; ct < 4; ++ct) {
      #pragma unroll
      for (int r = 0; r < 4; ++r) O[ct][r] *= alpha[r];
    }

    // ---- P A-fragment: own rows, fp32 -> 3-term split (wave-local) ---------
    bf16x8 ph, pm, pl;
    {
      const float* pp = &Pb[(16 * w + ln) * 36 + 8 * q];
      const float4 p0 = ((const float4*)pp)[0];
      const float4 p1 = ((const float4*)pp)[1];
      const float pvv[8] = {p0.x, p0.y, p0.z, p0.w, p1.x, p1.y, p1.z, p1.w};
      union { bf16x8 v; unsigned short e[8]; } uh, um, ul;
      #pragma unroll
      for (int j = 0; j < 8; ++j) {
        unsigned short h, m, l;
        split3(pvv[j], h, m, l);
        uh.e[j] = h; um.e[j] = m; ul.e[j] = l;
      }
      ph = uh.v; pm = um.v; pl = ul.v;
    }

    // ---- O += P @ V, 6-product (r5 order) ----------------------------------
    #pragma unroll
    for (int ct = 0; ct < 4; ++ct) {
      const int vo = (16 * ct + ln) * 40 + 8 * q;
      const bf16x8 vvh = ld16B(&Vhs[vo]);
      const bf16x8 vvm = ld16B(&Vms[vo]);
      const bf16x8 vvl = ld16B(&Vls[vo]);
      O[ct] = MFMA16(ph, vvh, O[ct]);
      O[ct] = MFMA16(ph, vvm, O[ct]);
      O[ct] = MFMA16(pm, vvh, O[ct]);
      O[ct] = MFMA16(pm, vvm, O[ct]);
      O[ct] = MFMA16(ph, vvl, O[ct]);
      O[ct] = MFMA16(pl, vvh, O[ct]);
    }
  }

  // ---- epilogue: X += O/l; fused channel-mean on last layer ----------------
  float linv[4];
  #pragma unroll
  for (int r = 0; r < 4; ++r) linv[r] = 1.0f / l_run[r];
  #pragma unroll
  for (int r = 0; r < 4; ++r) {
    const int row = i0 + 16 * w + 4 * q + r;
    float srow = 0.f;
    #pragma unroll
    for (int ct = 0; ct < 4; ++ct) {
      float* xp = X + base + (size_t)row * 64 + ln + 16 * ct;
      const float nv = *xp + O[ct][r] * linv[r];
      *xp = nv;
      srow += nv;
    }
    if (meanout) {
      #pragma unroll
      for (int mk = 1; mk <= 8; mk <<= 1)
        srow += __shfl_xor(srow, mk, 64);
      if (ln == 0) meanout[(size_t)b * DIMN + row] = srow * (1.0f / 64.0f);
    }
  }
}

// ---------------------------------------------------------------------------
// 4) head stage 2: pred[b,k] = meanv[b,:] . last_W[k,:] + last_b[k]
// ---------------------------------------------------------------------------
__global__ __launch_bounds__(256) void k_head2(
    const float* __restrict__ meanv, const float* __restrict__ lW,
    const float* __restrict__ lb, float* __restrict__ out) {
  __shared__ float red[256];
  const int b   = blockIdx.x;
  const int tid = threadIdx.x;
  float acc[NCLS];
  #pragma unroll
  for (int k = 0; k < NCLS; ++k) acc[k] = 0.f;
  for (int n = tid; n < DIMN; n += 256) {
    const float m = meanv[(size_t)b * DIMN + n];
    #pragma unroll
    for (int k = 0; k < NCLS; ++k)
      acc[k] = fmaf(m, lW[k * DIMN + n], acc[k]);
  }
  for (int k = 0; k < NCLS; ++k) {
    red[tid] = acc[k];
    __syncthreads();
    for (int s = 128; s > 0; s >>= 1) {
      if (tid < s) red[tid] += red[tid + s];
      __syncthreads();
    }
    if (tid == 0) out[b * NCLS + k] = red[0] + lb[k];
    __syncthreads();
  }
}

// ===========================================================================
// FALLBACK PATH (round-3 kernels, ws too small): proven absmax 0.0
// ===========================================================================
__global__ __launch_bounds__(256) void k_qkv(
    const float* __restrict__ X,
    const float* __restrict__ WQ, const float* __restrict__ WK,
    const float* __restrict__ WV,
    float* __restrict__ Q, float* __restrict__ K, float* __restrict__ V) {
  __shared__ float xs[16][64];
  const int c  = threadIdx.x & 63;
  const int tg = threadIdx.x >> 6;
  const size_t t0 = (size_t)blockIdx.x * 16;
  #pragma unroll
  for (int r = tg; r < 16; r += 4)
    xs[r][c] = X[(t0 + r) * 64 + c];
  __syncthreads();
  float qa[4] = {0.f,0.f,0.f,0.f};
  float ka[4] = {0.f,0.f,0.f,0.f};
  float va[4] = {0.f,0.f,0.f,0.f};
  for (int j = 0; j < 64; ++j) {
    const float wq = WQ[j * 64 + c];
    const float wk = WK[j * 64 + c];
    const float wv = WV[j * 64 + c];
    #pragma unroll
    for (int r = 0; r < 4; ++r) {
      const float x = xs[tg * 4 + r][j];
      qa[r] = fmaf(x, wq, qa[r]);
      ka[r] = fmaf(x, wk, ka[r]);
      va[r] = fmaf(x, wv, va[r]);
    }
  }
  #pragma unroll
  for (int r = 0; r < 4; ++r) {
    const size_t idx = (t0 + tg * 4 + r) * 64 + c;
    Q[idx] = qa[r]; K[idx] = ka[r]; V[idx] = va[r];
  }
}

__global__ __launch_bounds__(256) void k_attn_mfma(
    const float* __restrict__ Qg, const float* __restrict__ Kg,
    const float* __restrict__ Vg, float* __restrict__ X) {
  __shared__ __align__(16) unsigned short Kh[32 * 72];
  __shared__ __align__(16) unsigned short Km[32 * 72];
  __shared__ __align__(16) unsigned short Kl[32 * 72];
  __shared__ __align__(16) unsigned short Vh[64 * 40];
  __shared__ __align__(16) unsigned short Vm[64 * 40];
  __shared__ __align__(16) unsigned short Vl[64 * 40];
  __shared__ __align__(16) float Pb[64 * 36];

  const int tid  = threadIdx.x;
  const int w    = tid >> 6;
  const int lane = tid & 63;
  const int ln   = lane & 15;
  const int q    = lane >> 4;
  const int b    = blockIdx.y;
  const int i0   = blockIdx.x * 64;
  const size_t base = (size_t)b * (DIMN * 64);
  const float scale = 0.03125f;

  const float* Kbase = Kg + base;
  const float* Vbase = Vg + base;

  bf16x8 qh[2], qm[2], ql[2];
  {
    const int mrow = i0 + 16 * w + ln;
    const float* qp = Qg + base + (size_t)mrow * 64 + 8 * q;
    #pragma unroll
    for (int s = 0; s < 2; ++s) {
      const float4 x0 = ((const float4*)(qp + 32 * s))[0];
      const float4 x1 = ((const float4*)(qp + 32 * s))[1];
      const float xv[8] = {x0.x, x0.y, x0.z, x0.w, x1.x, x1.y, x1.z, x1.w};
      union { bf16x8 v; unsigned short e[8]; } uh, um, ul;
      #pragma unroll
      for (int j = 0; j < 8; ++j) {
        unsigned short h, m, l;
        split3(xv[j], h, m, l);
        uh.e[j] = h; um.e[j] = m; ul.e[j] = l;
      }
      qh[s] = uh.v; qm[s] = um.v; ql[s] = ul.v;
    }
  }

  f32x4 O[4];
  #pragma unroll
  for (int ct = 0; ct < 4; ++ct) O[ct] = (f32x4){0.f, 0.f, 0.f, 0.f};
  float m_run[4] = {-INFINITY, -INFINITY, -INFINITY, -INFINITY};
  float l_run[4] = {0.f, 0.f, 0.f, 0.f};

  for (int kt = 0; kt < 32; ++kt) {
    __syncthreads();
    {
      const int j  = tid >> 3;
      const int dq = tid & 7;
      const float* kp = Kbase + (size_t)(kt * 32 + j) * 64 + 8 * dq;
      const float4 a0 = ((const float4*)kp)[0];
      const float4 a1 = ((const float4*)kp)[1];
      const float xv[8] = {a0.x, a0.y, a0.z, a0.w, a1.x, a1.y, a1.z, a1.w};
      const int o = j * 72 + 8 * dq;
      us4 hh[2], mm[2], llv[2];
      #pragma unroll
      for (int e = 0; e < 8; ++e) {
        unsigned short h, m, l;
        split3(xv[e], h, m, l);
        hh[e >> 2][e & 3] = h; mm[e >> 2][e & 3] = m; llv[e >> 2][e & 3] = l;
      }
      *(us4*)&Kh[o] = hh[0];  *(us4*)&Kh[o + 4] = hh[1];
      *(us4*)&Km[o] = mm[0];  *(us4*)&Km[o + 4] = mm[1];
      *(us4*)&Kl[o] = llv[0]; *(us4*)&Kl[o + 4] = llv[1];
    }
    {
      const int jp = tid >> 4;
      const int cq = tid & 15;
      const float* vp = Vbase + (size_t)(kt * 32 + 2 * jp) * 64 + 4 * cq;
      const float4 a = *(const float4*)vp;
      const float4 bb = *(const float4*)(vp + 64);
      const float av[4] = {a.x, a.y, a.z, a.w};
      const float bv[4] = {bb.x, bb.y, bb.z, bb.w};
      #pragma unroll
      for (int e = 0; e < 4; ++e) {
        const int c = 4 * cq + e;
        unsigned short h1, m1, l1, h2, m2, l2;
        split3(av[e], h1, m1, l1);
        split3(bv[e], h2, m2, l2);
        *(unsigned int*)&Vh[c * 40 + 2 * jp] = (unsigned)h1 | ((unsigned)h2 << 16);
        *(unsigned int*)&Vm[c * 40 + 2 * jp] = (unsigned)m1 | ((unsigned)m2 << 16);
        *(unsigned int*)&Vl[c * 40 + 2 * jp] = (unsigned)l1 | ((unsigned)l2 << 16);
      }
    }
    __syncthreads();

    f32x4 sacc[2];
    #pragma unroll
    for (int ct = 0; ct < 2; ++ct) {
      f32x4 a = (f32x4){0.f, 0.f, 0.f, 0.f};
      #pragma unroll
      for (int s = 0; s < 2; ++s) {
        const int ko = (16 * ct + ln) * 72 + 32 * s + 8 * q;
        const bf16x8 bh = ld16B(&Kh[ko]);
        const bf16x8 bm = ld16B(&Km[ko]);
        const bf16x8 bl = ld16B(&Kl[ko]);
        a = MFMA16(ql[s], bh, a);
        a = MFMA16(qh[s], bl, a);
        a = MFMA16(qm[s], bm, a);
        a = MFMA16(qm[s], bh, a);
        a = MFMA16(qh[s], bm, a);
        a = MFMA16(qh[s], bh, a);
      }
      sacc[ct] = a;
    }

    float rmax[4];
    #pragma unroll
    for (int r = 0; r < 4; ++r)
      rmax[r] = fmaxf(sacc[0][r], sacc[1][r]);
    #pragma unroll
    for (int mk = 1; mk <= 8; mk <<= 1) {
      #pragma unroll
      for (int r = 0; r < 4; ++r)
        rmax[r] = fmaxf(rmax[r], __shfl_xor(rmax[r], mk, 64));
    }
    float alpha[4], rsum[4];
    #pragma unroll
    for (int r = 0; r < 4; ++r) {
      const float mnew = fmaxf(m_run[r], rmax[r] * scale);
      alpha[r] = __expf(m_run[r] - mnew);
      m_run[r] = mnew;
      rsum[r] = 0.f;
    }
    #pragma unroll
    for (int ct = 0; ct < 2; ++ct) {
      #pragma unroll
      for (int r = 0; r < 4; ++r) {
        const float pv = __expf(sacc[ct][r] * scale - m_run[r]);
        rsum[r] += pv;
        Pb[(16 * w + 4 * q + r) * 36 + ln + 16 * ct] = pv;
      }
    }
    #pragma unroll
    for (int mk = 1; mk <= 8; mk <<= 1) {
      #pragma unroll
      for (int r = 0; r < 4; ++r)
        rsum[r] += __shfl_xor(rsum[r], mk, 64);
    }
    #pragma unroll
    for (int r = 0; r < 4; ++r)
      l_run[r] = l_run[r] * alpha[r] + rsum[r];

    #pragma unroll
    for (int ct = 0; ct < 4; ++ct) {
      #pragma unroll
      for (int r = 0; r < 4; ++r) O[ct][r] *= alpha[r];
    }

    bf16x8 ph, pm, pl;
    {
      const float* pp = &Pb[(16 * w + ln) * 36 + 8 * q];
      const float4 p0 = ((const float4*)pp)[0];
      const float4 p1 = ((const float4*)pp)[1];
      const float pvv[8] = {p0.x, p0.y, p0.z, p0.w, p1.x, p1.y, p1.z, p1.w};
      union { bf16x8 v; unsigned short e[8]; } uh, um, ul;
      #pragma unroll
      for (int j = 0; j < 8; ++j) {
        unsigned short h, m, l;
        split3(pvv[j], h, m, l);
        uh.e[j] = h; um.e[j] = m; ul.e[j] = l;
      }
      ph = uh.v; pm = um.v; pl = ul.v;
    }

    #pragma unroll
    for (int ct = 0; ct < 4; ++ct) {
      const int vo = (16 * ct + ln) * 40 + 8 * q;
      const bf16x8 vvh = ld16B(&Vh[vo]);
      const bf16x8 vvm = ld16B(&Vm[vo]);
      const bf16x8 vvl = ld16B(&Vl[vo]);
      O[ct] = MFMA16(ph, vvh, O[ct]);
      O[ct] = MFMA16(ph, vvm, O[ct]);
      O[ct] = MFMA16(pm, vvh, O[ct]);
      O[ct] = MFMA16(pm, vvm, O[ct]);
      O[ct] = MFMA16(ph, vvl, O[ct]);
      O[ct] = MFMA16(pl, vvh, O[ct]);
    }
  }

  float linv[4];
  #pragma unroll
  for (int r = 0; r < 4; ++r) linv[r] = 1.0f / l_run[r];
  #pragma unroll
  for (int ct = 0; ct < 4; ++ct) {
    #pragma unroll
    for (int r = 0; r < 4; ++r) {
      float* xp = X + base + (size_t)(i0 + 16 * w + 4 * q + r) * 64 + ln + 16 * ct;
      *xp += O[ct][r] * linv[r];
    }
  }
}

__global__ __launch_bounds__(256) void k_head(
    const float* __restrict__ X, const float* __restrict__ lW,
    const float* __restrict__ lb, float* __restrict__ out) {
  __shared__ float meanv[DIMN];
  __shared__ float red[256];
  const int b    = blockIdx.x;
  const int tid  = threadIdx.x;
  const int lane = tid & 63;
  const int w    = tid >> 6;
  const float* Xb = X + (size_t)b * DIMN * 64;
  for (int n = w; n < DIMN; n += 4) {
    float v = Xb[(size_t)n * 64 + lane];
    #pragma unroll
    for (int off = 32; off > 0; off >>= 1)
      v += __shfl_down(v, off, 64);
    if (lane == 0) meanv[n] = v * (1.0f / 64.0f);
  }
  __syncthreads();
  float acc[NCLS];
  #pragma unroll
  for (int k = 0; k < NCLS; ++k) acc[k] = 0.f;
  for (int n = tid; n < DIMN; n += 256) {
    const float m = meanv[n];
    #pragma unroll
    for (int k = 0; k < NCLS; ++k)
      acc[k] = fmaf(m, lW[k * DIMN + n], acc[k]);
  }
  for (int k = 0; k < NCLS; ++k) {
    red[tid] = acc[k];
    __syncthreads();
    for (int s = 128; s > 0; s >>= 1) {
      if (tid < s) red[tid] += red[tid + s];
      __syncthreads();
    }
    if (tid == 0) out[b * NCLS + k] = red[0] + lb[k];
    __syncthreads();
  }
}

// ---------------------------------------------------------------------------
// launch
// ---------------------------------------------------------------------------
extern "C" void kernel_launch(void* const* d_in, const int* in_sizes, int n_in,
                              void* d_out, int out_size, void* d_ws, size_t ws_size,
                              hipStream_t stream) {
  const float* image = (const float*)d_in[0];
  const float* WV    = (const float*)d_in[1];
  const float* WK    = (const float*)d_in[2];
  const float* WQ    = (const float*)d_in[3];
  const float* lW    = (const float*)d_in[4];
  const float* lb    = (const float*)d_in[5];
  float* out = (float*)d_out;

  float* ws = (float*)d_ws;
  const size_t NELEM = (size_t)BB * DIMN * CCH;   // 2,097,152

  const size_t need_fast = 2 * NELEM * sizeof(float)          // X, Q
                         + 6 * NELEM * sizeof(unsigned short) // K/V splits
                         + (size_t)BB * DIMN * sizeof(float); // meanv

  if (ws_size >= need_fast) {
    float* X = ws;
    float* Q = ws + NELEM;
    unsigned short* Kh  = (unsigned short*)(ws + 2 * NELEM);
    unsigned short* Km  = Kh + NELEM;
    unsigned short* Kl  = Kh + 2 * NELEM;
    unsigned short* VhT = Kh + 3 * NELEM;
    unsigned short* VmT = Kh + 4 * NELEM;
    unsigned short* VlT = Kh + 5 * NELEM;
    float* meanv = (float*)(Kh + 6 * NELEM);

    k_transpose<<<dim3(DIMN / 64, BB), 256, 0, stream>>>(image, X);
    for (int layer = 0; layer < 8; ++layer) {
      k_qkv_split<<<(BB * DIMN) / 16, 256, 0, stream>>>(
          X, WQ, WK, WV, Q, Kh, Km, Kl, VhT, VmT, VlT);
      k_attn_s3<<<dim3(DIMN / 32, BB), 128, 0, stream>>>(
          Q, Kh, Km, Kl, VhT, VmT, VlT, X, (layer == 7) ? meanv : nullptr);
    }
    k_head2<<<BB, 256, 0, stream>>>(meanv, lW, lb, out);
  } else {
    float* X = ws;
    float* Q = ws + NELEM;
    float* K = ws + 2 * NELEM;
    float* V = ws + 3 * NELEM;
    k_transpose<<<dim3(DIMN / 64, BB), 256, 0, stream>>>(image, X);
    for (int layer = 0; layer < 8; ++layer) {
      k_qkv<<<(BB * DIMN) / 16, 256, 0, stream>>>(X, WQ, WK, WV, Q, K, V);
      k_attn_mfma<<<dim3(DIMN / 64, BB), 256, 0, stream>>>(Q, K, V, X);
    }
    k_head<<<BB, 256, 0, stream>>>(X, lW, lb, out);
  }
}

// Round 8
// 931.280 us; speedup vs baseline: 1.5288x; 1.0538x over previous
//
#include <hip/hip_runtime.h>
#include <math.h>

#define BB    32
#define CCH   64
#define DIMN  1024
#define NCLS  10

typedef __attribute__((ext_vector_type(8))) short bf16x8;
typedef __attribute__((ext_vector_type(4))) float f32x4;
typedef __attribute__((ext_vector_type(4))) unsigned short us4;
typedef __attribute__((ext_vector_type(8))) unsigned short us8;

#define MFMA16(a, b, c) __builtin_amdgcn_mfma_f32_16x16x32_bf16(a, b, c, 0, 0, 0)

__device__ __forceinline__ unsigned short f2bf(float x) {
  unsigned u = __float_as_uint(x);
  unsigned r = u + 0x7fffu + ((u >> 16) & 1u);   // round-to-nearest-even
  return (unsigned short)(r >> 16);
}
__device__ __forceinline__ float bf2f(unsigned short h) {
  return __uint_as_float(((unsigned)h) << 16);
}
// x == h + m + l to ~2^-26 relative
__device__ __forceinline__ void split3(float x, unsigned short& h,
                                       unsigned short& m, unsigned short& l) {
  h = f2bf(x); float hf = bf2f(h);
  float r = x - hf;
  m = f2bf(r); float mf = bf2f(m);
  l = f2bf(r - mf);
}
__device__ __forceinline__ bf16x8 ld16B(const unsigned short* p) {
  union { us8 u; bf16x8 v; } c;
  c.u = *(const us8*)p;           // 16B-aligned -> ds_read_b128
  return c.v;
}

// ---------------------------------------------------------------------------
// 1) transpose: image (B,C,DIM) -> X (B,DIM,C)
// ---------------------------------------------------------------------------
__global__ __launch_bounds__(256) void k_transpose(const float* __restrict__ img,
                                                   float* __restrict__ X) {
  __shared__ float tile[64][65];
  const int b  = blockIdx.y;
  const int n0 = blockIdx.x * 64;
  const int tx = threadIdx.x & 63;
  const int ty = threadIdx.x >> 6;
  const float* src = img + (size_t)b * CCH * DIMN;
  #pragma unroll
  for (int c = ty; c < 64; c += 4)
    tile[c][tx] = src[(size_t)c * DIMN + n0 + tx];
  __syncthreads();
  float* dst = X + (size_t)b * DIMN * CCH;
  #pragma unroll
  for (int nn = ty; nn < 64; nn += 4)
    dst[(size_t)(n0 + nn) * CCH + tx] = tile[tx][nn];
}

// ---------------------------------------------------------------------------
// 2) QKV + per-layer pre-split (unchanged from r5: proven absmax 0.0):
//    Q fp32; K 3-term bf16 [t][c]; V 3-term bf16 transposed+tiled [b][kt][c][32]
// ---------------------------------------------------------------------------
__global__ __launch_bounds__(256) void k_qkv_split(
    const float* __restrict__ X,
    const float* __restrict__ WQ, const float* __restrict__ WK,
    const float* __restrict__ WV,
    float* __restrict__ Q,
    unsigned short* __restrict__ Kh, unsigned short* __restrict__ Km,
    unsigned short* __restrict__ Kl,
    unsigned short* __restrict__ VhT, unsigned short* __restrict__ VmT,
    unsigned short* __restrict__ VlT) {
  __shared__ float xs[16][64];
  __shared__ unsigned short vs[3][16][64];
  const int c  = threadIdx.x & 63;
  const int tg = threadIdx.x >> 6;
  const size_t t0 = (size_t)blockIdx.x * 16;
  #pragma unroll
  for (int r = tg; r < 16; r += 4)
    xs[r][c] = X[(t0 + r) * 64 + c];
  __syncthreads();
  float qa[4] = {0.f,0.f,0.f,0.f};
  float ka[4] = {0.f,0.f,0.f,0.f};
  float va[4] = {0.f,0.f,0.f,0.f};
  for (int j = 0; j < 64; ++j) {
    const float wq = WQ[j * 64 + c];
    const float wk = WK[j * 64 + c];
    const float wv = WV[j * 64 + c];
    #pragma unroll
    for (int r = 0; r < 4; ++r) {
      const float x = xs[tg * 4 + r][j];
      qa[r] = fmaf(x, wq, qa[r]);
      ka[r] = fmaf(x, wk, ka[r]);
      va[r] = fmaf(x, wv, va[r]);
    }
  }
  #pragma unroll
  for (int r = 0; r < 4; ++r) {
    const int t = tg * 4 + r;
    const size_t idx = (t0 + t) * 64 + c;
    Q[idx] = qa[r];
    unsigned short h, m, l;
    split3(ka[r], h, m, l);
    Kh[idx] = h; Km[idx] = m; Kl[idx] = l;
    split3(va[r], h, m, l);
    vs[0][t][c] = h; vs[1][t][c] = m; vs[2][t][c] = l;
  }
  __syncthreads();
  {
    const int row  = threadIdx.x >> 2;        // c: 0..63
    const int part = threadIdx.x & 3;         // 4-token group
    const size_t bofs = (t0 >> 10) * ((size_t)DIMN * 64);
    const size_t kt   = (t0 & 1023) >> 5;
    const size_t tin  = (t0 & 31) + part * 4;
    unsigned short* dst[3] = {VhT, VmT, VlT};
    #pragma unroll
    for (int term = 0; term < 3; ++term) {
      us4 pk;
      #pragma unroll
      for (int i = 0; i < 4; ++i) pk[i] = vs[term][part * 4 + i][row];
      *(us4*)&dst[term][bofs + kt * 2048 + (size_t)row * 32 + tin] = pk;
    }
  }
}

// ---------------------------------------------------------------------------
// 3) MFMA flash attention — r5 kernel + XCD-AWARE BLOCK SWIZZLE.
//    r5/r6/r7 triangulation: perf tracks waves/CU; FETCH_SIZE=106MB vs 32MB
//    unique data (3.3x HBM refetch, 1.1 TB/s x 88us ~ whole dispatch) —
//    the 16 Q-tile blocks per batch were scattered over all 8 XCDs, each L2
//    streaming the full 24MB K/V set. Swizzle: flatten grid to 512 and pin
//    each batch's 16 blocks to ONE XCD (4 batches/XCD -> 3MB K/V fits 4MB L2).
//    Pure index remap — arithmetic EXACTLY r5's => bit-identical (absmax 0.0).
//    LDS: K 13.8 + V^T 15.4 + P 9.2 = 38.4 KB.
// ---------------------------------------------------------------------------
__global__ __launch_bounds__(256) void k_attn_s(
    const float* __restrict__ Qg,
    const unsigned short* __restrict__ Kh, const unsigned short* __restrict__ Km,
    const unsigned short* __restrict__ Kl,
    const unsigned short* __restrict__ VhT, const unsigned short* __restrict__ VmT,
    const unsigned short* __restrict__ VlT,
    float* __restrict__ X, float* __restrict__ meanout) {
  __shared__ __align__(16) unsigned short Khs[32 * 72];
  __shared__ __align__(16) unsigned short Kms[32 * 72];
  __shared__ __align__(16) unsigned short Kls[32 * 72];
  __shared__ __align__(16) unsigned short Vhs[64 * 40];   // V^T: [c][j]
  __shared__ __align__(16) unsigned short Vms[64 * 40];
  __shared__ __align__(16) unsigned short Vls[64 * 40];
  __shared__ __align__(16) float Pb[64 * 36];             // fp32 P round-trip

  const int tid  = threadIdx.x;
  const int w    = tid >> 6;
  const int lane = tid & 63;
  const int ln   = lane & 15;
  const int q    = lane >> 4;

  // XCD-aware swizzle: XCD = bid % 8 (HW round-robin heuristic; locality only)
  const int bid = blockIdx.x;             // 0..511
  const int xcd = bid & 7;
  const int seq = bid >> 3;               // 0..63
  const int b   = xcd * 4 + (seq >> 4);   // 4 batches per XCD
  const int i0  = (seq & 15) * 64;        // 16 Q-tiles per batch

  const size_t base = (size_t)b * (DIMN * 64);
  const float scale = 0.03125f;

  // staging addresses (tile-contiguous: tile kt = 4 KB at base + kt*2048)
  const int kj = tid >> 3, kg = tid & 7;
  const int vc = tid >> 2, vg = tid & 3;
  const int klo = kj * 72 + kg * 8;
  const int vlo = vc * 40 + vg * 8;

  // ---- Q fragments: 3-term split, 2 k-chunks (once per block) --------------
  bf16x8 qh[2], qm[2], ql[2];
  {
    const int mrow = i0 + 16 * w + ln;
    const float* qp = Qg + base + (size_t)mrow * 64 + 8 * q;
    #pragma unroll
    for (int s = 0; s < 2; ++s) {
      const float4 x0 = ((const float4*)(qp + 32 * s))[0];
      const float4 x1 = ((const float4*)(qp + 32 * s))[1];
      const float xv[8] = {x0.x, x0.y, x0.z, x0.w, x1.x, x1.y, x1.z, x1.w};
      union { bf16x8 v; unsigned short e[8]; } uh, um, ul;
      #pragma unroll
      for (int j = 0; j < 8; ++j) {
        unsigned short h, m, l;
        split3(xv[j], h, m, l);
        uh.e[j] = h; um.e[j] = m; ul.e[j] = l;
      }
      qh[s] = uh.v; qm[s] = um.v; ql[s] = ul.v;
    }
  }

  f32x4 O[4];
  #pragma unroll
  for (int ct = 0; ct < 4; ++ct) O[ct] = (f32x4){0.f, 0.f, 0.f, 0.f};
  float m_run[4] = {-INFINITY, -INFINITY, -INFINITY, -INFINITY};
  float l_run[4] = {0.f, 0.f, 0.f, 0.f};

  for (int kt = 0; kt < 32; ++kt) {
    __syncthreads();   // previous iteration's K/V readers done

    // ---- stage pre-split K/V tile: pure 16B copies -------------------------
    {
      const size_t tof = base + (size_t)kt * 2048 + tid * 8;  // shorts
      const us8 a0 = *(const us8*)&Kh[tof];
      const us8 a1 = *(const us8*)&Km[tof];
      const us8 a2 = *(const us8*)&Kl[tof];
      const us8 b0 = *(const us8*)&VhT[tof];
      const us8 b1 = *(const us8*)&VmT[tof];
      const us8 b2 = *(const us8*)&VlT[tof];
      *(us8*)&Khs[klo] = a0;
      *(us8*)&Kms[klo] = a1;
      *(us8*)&Kls[klo] = a2;
      *(us8*)&Vhs[vlo] = b0;
      *(us8*)&Vms[vlo] = b1;
      *(us8*)&Vls[vlo] = b2;
    }
    __syncthreads();

    // ---- S strip = Q . K^T via 6-product compensated MFMA ------------------
    f32x4 sacc[2];
    #pragma unroll
    for (int ct = 0; ct < 2; ++ct) {
      f32x4 a = (f32x4){0.f, 0.f, 0.f, 0.f};
      #pragma unroll
      for (int s = 0; s < 2; ++s) {
        const int ko = (16 * ct + ln) * 72 + 32 * s + 8 * q;
        const bf16x8 bh = ld16B(&Khs[ko]);
        const bf16x8 bm = ld16B(&Kms[ko]);
        const bf16x8 bl = ld16B(&Kls[ko]);
        a = MFMA16(ql[s], bh, a);
        a = MFMA16(qh[s], bl, a);
        a = MFMA16(qm[s], bm, a);
        a = MFMA16(qm[s], bh, a);
        a = MFMA16(qh[s], bm, a);
        a = MFMA16(qh[s], bh, a);
      }
      sacc[ct] = a;
    }

    // ---- wave-local online softmax -----------------------------------------
    float rmax[4];
    #pragma unroll
    for (int r = 0; r < 4; ++r)
      rmax[r] = fmaxf(sacc[0][r], sacc[1][r]);
    #pragma unroll
    for (int mk = 1; mk <= 8; mk <<= 1) {
      #pragma unroll
      for (int r = 0; r < 4; ++r)
        rmax[r] = fmaxf(rmax[r], __shfl_xor(rmax[r], mk, 64));
    }
    float alpha[4], rsum[4];
    #pragma unroll
    for (int r = 0; r < 4; ++r) {
      const float mnew = fmaxf(m_run[r], rmax[r] * scale);
      alpha[r] = __expf(m_run[r] - mnew);
      m_run[r] = mnew;
      rsum[r] = 0.f;
    }
    #pragma unroll
    for (int ct = 0; ct < 2; ++ct) {
      #pragma unroll
      for (int r = 0; r < 4; ++r) {
        const float pv = __expf(sacc[ct][r] * scale - m_run[r]);
        rsum[r] += pv;
        Pb[(16 * w + 4 * q + r) * 36 + ln + 16 * ct] = pv;   // fp32, wave-local
      }
    }
    #pragma unroll
    for (int mk = 1; mk <= 8; mk <<= 1) {
      #pragma unroll
      for (int r = 0; r < 4; ++r)
        rsum[r] += __shfl_xor(rsum[r], mk, 64);
    }
    #pragma unroll
    for (int r = 0; r < 4; ++r)
      l_run[r] = l_run[r] * alpha[r] + rsum[r];

    #pragma unroll
    for (int ct = 0; ct < 4; ++ct) {
      #pragma unroll
      for (int r = 0; r < 4; ++r) O[ct][r] *= alpha[r];
    }

    // ---- P A-fragment: own rows, fp32 -> 3-term split ----------------------
    bf16x8 ph, pm, pl;
    {
      const float* pp = &Pb[(16 * w + ln) * 36 + 8 * q];
      const float4 p0 = ((const float4*)pp)[0];
      const float4 p1 = ((const float4*)pp)[1];
      const float pvv[8] = {p0.x, p0.y, p0.z, p0.w, p1.x, p1.y, p1.z, p1.w};
      union { bf16x8 v; unsigned short e[8]; } uh, um, ul;
      #pragma unroll
      for (int j = 0; j < 8; ++j) {
        unsigned short h, m, l;
        split3(pvv[j], h, m, l);
        uh.e[j] = h; um.e[j] = m; ul.e[j] = l;
      }
      ph = uh.v; pm = um.v; pl = ul.v;
    }

    // ---- O += P @ V, 6-product ---------------------------------------------
    #pragma unroll
    for (int ct = 0; ct < 4; ++ct) {
      const int vo = (16 * ct + ln) * 40 + 8 * q;
      const bf16x8 vvh = ld16B(&Vhs[vo]);
      const bf16x8 vvm = ld16B(&Vms[vo]);
      const bf16x8 vvl = ld16B(&Vls[vo]);
      O[ct] = MFMA16(ph, vvh, O[ct]);
      O[ct] = MFMA16(ph, vvm, O[ct]);
      O[ct] = MFMA16(pm, vvh, O[ct]);
      O[ct] = MFMA16(pm, vvm, O[ct]);
      O[ct] = MFMA16(ph, vvl, O[ct]);
      O[ct] = MFMA16(pl, vvh, O[ct]);
    }
  }

  // ---- epilogue: X += O/l; fused channel-mean on last layer ----------------
  float linv[4];
  #pragma unroll
  for (int r = 0; r < 4; ++r) linv[r] = 1.0f / l_run[r];
  #pragma unroll
  for (int r = 0; r < 4; ++r) {
    const int row = i0 + 16 * w + 4 * q + r;
    float srow = 0.f;
    #pragma unroll
    for (int ct = 0; ct < 4; ++ct) {
      float* xp = X + base + (size_t)row * 64 + ln + 16 * ct;
      const float nv = *xp + O[ct][r] * linv[r];
      *xp = nv;
      srow += nv;
    }
    if (meanout) {
      #pragma unroll
      for (int mk = 1; mk <= 8; mk <<= 1)
        srow += __shfl_xor(srow, mk, 64);
      if (ln == 0) meanout[(size_t)b * DIMN + row] = srow * (1.0f / 64.0f);
    }
  }
}

// ---------------------------------------------------------------------------
// 4) head stage 2: pred[b,k] = meanv[b,:] . last_W[k,:] + last_b[k]
// ---------------------------------------------------------------------------
__global__ __launch_bounds__(256) void k_head2(
    const float* __restrict__ meanv, const float* __restrict__ lW,
    const float* __restrict__ lb, float* __restrict__ out) {
  __shared__ float red[256];
  const int b   = blockIdx.x;
  const int tid = threadIdx.x;
  float acc[NCLS];
  #pragma unroll
  for (int k = 0; k < NCLS; ++k) acc[k] = 0.f;
  for (int n = tid; n < DIMN; n += 256) {
    const float m = meanv[(size_t)b * DIMN + n];
    #pragma unroll
    for (int k = 0; k < NCLS; ++k)
      acc[k] = fmaf(m, lW[k * DIMN + n], acc[k]);
  }
  for (int k = 0; k < NCLS; ++k) {
    red[tid] = acc[k];
    __syncthreads();
    for (int s = 128; s > 0; s >>= 1) {
      if (tid < s) red[tid] += red[tid + s];
      __syncthreads();
    }
    if (tid == 0) out[b * NCLS + k] = red[0] + lb[k];
    __syncthreads();
  }
}

// ===========================================================================
// FALLBACK PATH (round-3 kernels, ws too small): proven absmax 0.0
// ===========================================================================
__global__ __launch_bounds__(256) void k_qkv(
    const float* __restrict__ X,
    const float* __restrict__ WQ, const float* __restrict__ WK,
    const float* __restrict__ WV,
    float* __restrict__ Q, float* __restrict__ K, float* __restrict__ V) {
  __shared__ float xs[16][64];
  const int c  = threadIdx.x & 63;
  const int tg = threadIdx.x >> 6;
  const size_t t0 = (size_t)blockIdx.x * 16;
  #pragma unroll
  for (int r = tg; r < 16; r += 4)
    xs[r][c] = X[(t0 + r) * 64 + c];
  __syncthreads();
  float qa[4] = {0.f,0.f,0.f,0.f};
  float ka[4] = {0.f,0.f,0.f,0.f};
  float va[4] = {0.f,0.f,0.f,0.f};
  for (int j = 0; j < 64; ++j) {
    const float wq = WQ[j * 64 + c];
    const float wk = WK[j * 64 + c];
    const float wv = WV[j * 64 + c];
    #pragma unroll
    for (int r = 0; r < 4; ++r) {
      const float x = xs[tg * 4 + r][j];
      qa[r] = fmaf(x, wq, qa[r]);
      ka[r] = fmaf(x, wk, ka[r]);
      va[r] = fmaf(x, wv, va[r]);
    }
  }
  #pragma unroll
  for (int r = 0; r < 4; ++r) {
    const size_t idx = (t0 + tg * 4 + r) * 64 + c;
    Q[idx] = qa[r]; K[idx] = ka[r]; V[idx] = va[r];
  }
}

__global__ __launch_bounds__(256) void k_attn_mfma(
    const float* __restrict__ Qg, const float* __restrict__ Kg,
    const float* __restrict__ Vg, float* __restrict__ X) {
  __shared__ __align__(16) unsigned short Kh[32 * 72];
  __shared__ __align__(16) unsigned short Km[32 * 72];
  __shared__ __align__(16) unsigned short Kl[32 * 72];
  __shared__ __align__(16) unsigned short Vh[64 * 40];
  __shared__ __align__(16) unsigned short Vm[64 * 40];
  __shared__ __align__(16) unsigned short Vl[64 * 40];
  __shared__ __align__(16) float Pb[64 * 36];

  const int tid  = threadIdx.x;
  const int w    = tid >> 6;
  const int lane = tid & 63;
  const int ln   = lane & 15;
  const int q    = lane >> 4;
  const int b    = blockIdx.y;
  const int i0   = blockIdx.x * 64;
  const size_t base = (size_t)b * (DIMN * 64);
  const float scale = 0.03125f;

  const float* Kbase = Kg + base;
  const float* Vbase = Vg + base;

  bf16x8 qh[2], qm[2], ql[2];
  {
    const int mrow = i0 + 16 * w + ln;
    const float* qp = Qg + base + (size_t)mrow * 64 + 8 * q;
    #pragma unroll
    for (int s = 0; s < 2; ++s) {
      const float4 x0 = ((const float4*)(qp + 32 * s))[0];
      const float4 x1 = ((const float4*)(qp + 32 * s))[1];
      const float xv[8] = {x0.x, x0.y, x0.z, x0.w, x1.x, x1.y, x1.z, x1.w};
      union { bf16x8 v; unsigned short e[8]; } uh, um, ul;
      #pragma unroll
      for (int j = 0; j < 8; ++j) {
        unsigned short h, m, l;
        split3(xv[j], h, m, l);
        uh.e[j] = h; um.e[j] = m; ul.e[j] = l;
      }
      qh[s] = uh.v; qm[s] = um.v; ql[s] = ul.v;
    }
  }

  f32x4 O[4];
  #pragma unroll
  for (int ct = 0; ct < 4; ++ct) O[ct] = (f32x4){0.f, 0.f, 0.f, 0.f};
  float m_run[4] = {-INFINITY, -INFINITY, -INFINITY, -INFINITY};
  float l_run[4] = {0.f, 0.f, 0.f, 0.f};

  for (int kt = 0; kt < 32; ++kt) {
    __syncthreads();
    {
      const int j  = tid >> 3;
      const int dq = tid & 7;
      const float* kp = Kbase + (size_t)(kt * 32 + j) * 64 + 8 * dq;
      const float4 a0 = ((const float4*)kp)[0];
      const float4 a1 = ((const float4*)kp)[1];
      const float xv[8] = {a0.x, a0.y, a0.z, a0.w, a1.x, a1.y, a1.z, a1.w};
      const int o = j * 72 + 8 * dq;
      us4 hh[2], mm[2], llv[2];
      #pragma unroll
      for (int e = 0; e < 8; ++e) {
        unsigned short h, m, l;
        split3(xv[e], h, m, l);
        hh[e >> 2][e & 3] = h; mm[e >> 2][e & 3] = m; llv[e >> 2][e & 3] = l;
      }
      *(us4*)&Kh[o] = hh[0];  *(us4*)&Kh[o + 4] = hh[1];
      *(us4*)&Km[o] = mm[0];  *(us4*)&Km[o + 4] = mm[1];
      *(us4*)&Kl[o] = llv[0]; *(us4*)&Kl[o + 4] = llv[1];
    }
    {
      const int jp = tid >> 4;
      const int cq = tid & 15;
      const float* vp = Vbase + (size_t)(kt * 32 + 2 * jp) * 64 + 4 * cq;
      const float4 a = *(const float4*)vp;
      const float4 bb = *(const float4*)(vp + 64);
      const float av[4] = {a.x, a.y, a.z, a.w};
      const float bv[4] = {bb.x, bb.y, bb.z, bb.w};
      #pragma unroll
      for (int e = 0; e < 4; ++e) {
        const int c = 4 * cq + e;
        unsigned short h1, m1, l1, h2, m2, l2;
        split3(av[e], h1, m1, l1);
        split3(bv[e], h2, m2, l2);
        *(unsigned int*)&Vh[c * 40 + 2 * jp] = (unsigned)h1 | ((unsigned)h2 << 16);
        *(unsigned int*)&Vm[c * 40 + 2 * jp] = (unsigned)m1 | ((unsigned)m2 << 16);
        *(unsigned int*)&Vl[c * 40 + 2 * jp] = (unsigned)l1 | ((unsigned)l2 << 16);
      }
    }
    __syncthreads();

    f32x4 sacc[2];
    #pragma unroll
    for (int ct = 0; ct < 2; ++ct) {
      f32x4 a = (f32x4){0.f, 0.f, 0.f, 0.f};
      #pragma unroll
      for (int s = 0; s < 2; ++s) {
        const int ko = (16 * ct + ln) * 72 + 32 * s + 8 * q;
        const bf16x8 bh = ld16B(&Kh[ko]);
        const bf16x8 bm = ld16B(&Km[ko]);
        const bf16x8 bl = ld16B(&Kl[ko]);
        a = MFMA16(ql[s], bh, a);
        a = MFMA16(qh[s], bl, a);
        a = MFMA16(qm[s], bm, a);
        a = MFMA16(qm[s], bh, a);
        a = MFMA16(qh[s], bm, a);
        a = MFMA16(qh[s], bh, a);
      }
      sacc[ct] = a;
    }

    float rmax[4];
    #pragma unroll
    for (int r = 0; r < 4; ++r)
      rmax[r] = fmaxf(sacc[0][r], sacc[1][r]);
    #pragma unroll
    for (int mk = 1; mk <= 8; mk <<= 1) {
      #pragma unroll
      for (int r = 0; r < 4; ++r)
        rmax[r] = fmaxf(rmax[r], __shfl_xor(rmax[r], mk, 64));
    }
    float alpha[4], rsum[4];
    #pragma unroll
    for (int r = 0; r < 4; ++r) {
      const float mnew = fmaxf(m_run[r], rmax[r] * scale);
      alpha[r] = __expf(m_run[r] - mnew);
      m_run[r] = mnew;
      rsum[r] = 0.f;
    }
    #pragma unroll
    for (int ct = 0; ct < 2; ++ct) {
      #pragma unroll
      for (int r = 0; r < 4; ++r) {
        const float pv = __expf(sacc[ct][r] * scale - m_run[r]);
        rsum[r] += pv;
        Pb[(16 * w + 4 * q + r) * 36 + ln + 16 * ct] = pv;
      }
    }
    #pragma unroll
    for (int mk = 1; mk <= 8; mk <<= 1) {
      #pragma unroll
      for (int r = 0; r < 4; ++r)
        rsum[r] += __shfl_xor(rsum[r], mk, 64);
    }
    #pragma unroll
    for (int r = 0; r < 4; ++r)
      l_run[r] = l_run[r] * alpha[r] + rsum[r];

    #pragma unroll
    for (int ct = 0; ct < 4; ++ct) {
      #pragma unroll
      for (int r = 0; r < 4; ++r) O[ct][r] *= alpha[r];
    }

    bf16x8 ph, pm, pl;
    {
      const float* pp = &Pb[(16 * w + ln) * 36 + 8 * q];
      const float4 p0 = ((const float4*)pp)[0];
      const float4 p1 = ((const float4*)pp)[1];
      const float pvv[8] = {p0.x, p0.y, p0.z, p0.w, p1.x, p1.y, p1.z, p1.w};
      union { bf16x8 v; unsigned short e[8]; } uh, um, ul;
      #pragma unroll
      for (int j = 0; j < 8; ++j) {
        unsigned short h, m, l;
        split3(pvv[j], h, m, l);
        uh.e[j] = h; um.e[j] = m; ul.e[j] = l;
      }
      ph = uh.v; pm = um.v; pl = ul.v;
    }

    #pragma unroll
    for (int ct = 0; ct < 4; ++ct) {
      const int vo = (16 * ct + ln) * 40 + 8 * q;
      const bf16x8 vvh = ld16B(&Vh[vo]);
      const bf16x8 vvm = ld16B(&Vm[vo]);
      const bf16x8 vvl = ld16B(&Vl[vo]);
      O[ct] = MFMA16(ph, vvh, O[ct]);
      O[ct] = MFMA16(ph, vvm, O[ct]);
      O[ct] = MFMA16(pm, vvh, O[ct]);
      O[ct] = MFMA16(pm, vvm, O[ct]);
      O[ct] = MFMA16(ph, vvl, O[ct]);
      O[ct] = MFMA16(pl, vvh, O[ct]);
    }
  }

  float linv[4];
  #pragma unroll
  for (int r = 0; r < 4; ++r) linv[r] = 1.0f / l_run[r];
  #pragma unroll
  for (int ct = 0; ct < 4; ++ct) {
    #pragma unroll
    for (int r = 0; r < 4; ++r) {
      float* xp = X + base + (size_t)(i0 + 16 * w + 4 * q + r) * 64 + ln + 16 * ct;
      *xp += O[ct][r] * linv[r];
    }
  }
}

__global__ __launch_bounds__(256) void k_head(
    const float* __restrict__ X, const float* __restrict__ lW,
    const float* __restrict__ lb, float* __restrict__ out) {
  __shared__ float meanv[DIMN];
  __shared__ float red[256];
  const int b    = blockIdx.x;
  const int tid  = threadIdx.x;
  const int lane = tid & 63;
  const int w    = tid >> 6;
  const float* Xb = X + (size_t)b * DIMN * 64;
  for (int n = w; n < DIMN; n += 4) {
    float v = Xb[(size_t)n * 64 + lane];
    #pragma unroll
    for (int off = 32; off > 0; off >>= 1)
      v += __shfl_down(v, off, 64);
    if (lane == 0) meanv[n] = v * (1.0f / 64.0f);
  }
  __syncthreads();
  float acc[NCLS];
  #pragma unroll
  for (int k = 0; k < NCLS; ++k) acc[k] = 0.f;
  for (int n = tid; n < DIMN; n += 256) {
    const float m = meanv[n];
    #pragma unroll
    for (int k = 0; k < NCLS; ++k)
      acc[k] = fmaf(m, lW[k * DIMN + n], acc[k]);
  }
  for (int k = 0; k < NCLS; ++k) {
    red[tid] = acc[k];
    __syncthreads();
    for (int s = 128; s > 0; s >>= 1) {
      if (tid < s) red[tid] += red[tid + s];
      __syncthreads();
    }
    if (tid == 0) out[b * NCLS + k] = red[0] + lb[k];
    __syncthreads();
  }
}

// ---------------------------------------------------------------------------
// launch
// ---------------------------------------------------------------------------
extern "C" void kernel_launch(void* const* d_in, const int* in_sizes, int n_in,
                              void* d_out, int out_size, void* d_ws, size_t ws_size,
                              hipStream_t stream) {
  const float* image = (const float*)d_in[0];
  const float* WV    = (const float*)d_in[1];
  const float* WK    = (const float*)d_in[2];
  const float* WQ    = (const float*)d_in[3];
  const float* lW    = (const float*)d_in[4];
  const float* lb    = (const float*)d_in[5];
  float* out = (float*)d_out;

  float* ws = (float*)d_ws;
  const size_t NELEM = (size_t)BB * DIMN * CCH;   // 2,097,152

  const size_t need_fast = 2 * NELEM * sizeof(float)          // X, Q
                         + 6 * NELEM * sizeof(unsigned short) // K/V splits
                         + (size_t)BB * DIMN * sizeof(float); // meanv

  if (ws_size >= need_fast) {
    float* X = ws;
    float* Q = ws + NELEM;
    unsigned short* Kh  = (unsigned short*)(ws + 2 * NELEM);
    unsigned short* Km  = Kh + NELEM;
    unsigned short* Kl  = Kh + 2 * NELEM;
    unsigned short* VhT = Kh + 3 * NELEM;
    unsigned short* VmT = Kh + 4 * NELEM;
    unsigned short* VlT = Kh + 5 * NELEM;
    float* meanv = (float*)(Kh + 6 * NELEM);

    k_transpose<<<dim3(DIMN / 64, BB), 256, 0, stream>>>(image, X);
    for (int layer = 0; layer < 8; ++layer) {
      k_qkv_split<<<(BB * DIMN) / 16, 256, 0, stream>>>(
          X, WQ, WK, WV, Q, Kh, Km, Kl, VhT, VmT, VlT);
      k_attn_s<<<512, 256, 0, stream>>>(
          Q, Kh, Km, Kl, VhT, VmT, VlT, X, (layer == 7) ? meanv : nullptr);
    }
    k_head2<<<BB, 256, 0, stream>>>(meanv, lW, lb, out);
  } else {
    float* X = ws;
    float* Q = ws + NELEM;
    float* K = ws + 2 * NELEM;
    float* V = ws + 3 * NELEM;
    k_transpose<<<dim3(DIMN / 64, BB), 256, 0, stream>>>(image, X);
    for (int layer = 0; layer < 8; ++layer) {
      k_qkv<<<(BB * DIMN) / 16, 256, 0, stream>>>(X, WQ, WK, WV, Q, K, V);
      k_attn_mfma<<<dim3(DIMN / 64, BB), 256, 0, stream>>>(Q, K, V, X);
    }
    k_head<<<BB, 256, 0, stream>>>(X, lW, lb, out);
  }
}

// Round 9
// 857.303 us; speedup vs baseline: 1.6608x; 1.0863x over previous
//
#include <hip/hip_runtime.h>
#include <math.h>

#define BB    32
#define CCH   64
#define DIMN  1024
#define NCLS  10

typedef __attribute__((ext_vector_type(8))) short bf16x8;
typedef __attribute__((ext_vector_type(4))) float f32x4;
typedef __attribute__((ext_vector_type(4))) unsigned short us4;
typedef __attribute__((ext_vector_type(8))) unsigned short us8;

#define MFMA16(a, b, c) __builtin_amdgcn_mfma_f32_16x16x32_bf16(a, b, c, 0, 0, 0)

__device__ __forceinline__ unsigned short f2bf(float x) {
  unsigned u = __float_as_uint(x);
  unsigned r = u + 0x7fffu + ((u >> 16) & 1u);   // round-to-nearest-even
  return (unsigned short)(r >> 16);
}
__device__ __forceinline__ float bf2f(unsigned short h) {
  return __uint_as_float(((unsigned)h) << 16);
}
// x == h + m + l to ~2^-26 relative
__device__ __forceinline__ void split3(float x, unsigned short& h,
                                       unsigned short& m, unsigned short& l) {
  h = f2bf(x); float hf = bf2f(h);
  float r = x - hf;
  m = f2bf(r); float mf = bf2f(m);
  l = f2bf(r - mf);
}
__device__ __forceinline__ bf16x8 ld16B(const unsigned short* p) {
  union { us8 u; bf16x8 v; } c;
  c.u = *(const us8*)p;           // 16B-aligned -> ds_read_b128
  return c.v;
}

// ---------------------------------------------------------------------------
// 1) transpose: image (B,C,DIM) -> X (B,DIM,C)
// ---------------------------------------------------------------------------
__global__ __launch_bounds__(256) void k_transpose(const float* __restrict__ img,
                                                   float* __restrict__ X) {
  __shared__ float tile[64][65];
  const int b  = blockIdx.y;
  const int n0 = blockIdx.x * 64;
  const int tx = threadIdx.x & 63;
  const int ty = threadIdx.x >> 6;
  const float* src = img + (size_t)b * CCH * DIMN;
  #pragma unroll
  for (int c = ty; c < 64; c += 4)
    tile[c][tx] = src[(size_t)c * DIMN + n0 + tx];
  __syncthreads();
  float* dst = X + (size_t)b * DIMN * CCH;
  #pragma unroll
  for (int nn = ty; nn < 64; nn += 4)
    dst[(size_t)(n0 + nn) * CCH + tx] = tile[tx][nn];
}

// ---------------------------------------------------------------------------
// 2) QKV + per-layer pre-split (r5-proven): Q fp32; K 3-term bf16 [t][c];
//    V 3-term bf16 transposed+tiled [b][kt][c][32]
// ---------------------------------------------------------------------------
__global__ __launch_bounds__(256) void k_qkv_split(
    const float* __restrict__ X,
    const float* __restrict__ WQ, const float* __restrict__ WK,
    const float* __restrict__ WV,
    float* __restrict__ Q,
    unsigned short* __restrict__ Kh, unsigned short* __restrict__ Km,
    unsigned short* __restrict__ Kl,
    unsigned short* __restrict__ VhT, unsigned short* __restrict__ VmT,
    unsigned short* __restrict__ VlT) {
  __shared__ float xs[16][64];
  __shared__ unsigned short vs[3][16][64];
  const int c  = threadIdx.x & 63;
  const int tg = threadIdx.x >> 6;
  const size_t t0 = (size_t)blockIdx.x * 16;
  #pragma unroll
  for (int r = tg; r < 16; r += 4)
    xs[r][c] = X[(t0 + r) * 64 + c];
  __syncthreads();
  float qa[4] = {0.f,0.f,0.f,0.f};
  float ka[4] = {0.f,0.f,0.f,0.f};
  float va[4] = {0.f,0.f,0.f,0.f};
  for (int j = 0; j < 64; ++j) {
    const float wq = WQ[j * 64 + c];
    const float wk = WK[j * 64 + c];
    const float wv = WV[j * 64 + c];
    #pragma unroll
    for (int r = 0; r < 4; ++r) {
      const float x = xs[tg * 4 + r][j];
      qa[r] = fmaf(x, wq, qa[r]);
      ka[r] = fmaf(x, wk, ka[r]);
      va[r] = fmaf(x, wv, va[r]);
    }
  }
  #pragma unroll
  for (int r = 0; r < 4; ++r) {
    const int t = tg * 4 + r;
    const size_t idx = (t0 + t) * 64 + c;
    Q[idx] = qa[r];
    unsigned short h, m, l;
    split3(ka[r], h, m, l);
    Kh[idx] = h; Km[idx] = m; Kl[idx] = l;
    split3(va[r], h, m, l);
    vs[0][t][c] = h; vs[1][t][c] = m; vs[2][t][c] = l;
  }
  __syncthreads();
  {
    const int row  = threadIdx.x >> 2;
    const int part = threadIdx.x & 3;
    const size_t bofs = (t0 >> 10) * ((size_t)DIMN * 64);
    const size_t kt   = (t0 & 1023) >> 5;
    const size_t tin  = (t0 & 31) + part * 4;
    unsigned short* dst[3] = {VhT, VmT, VlT};
    #pragma unroll
    for (int term = 0; term < 3; ++term) {
      us4 pk;
      #pragma unroll
      for (int i = 0; i < 4; ++i) pk[i] = vs[term][part * 4 + i][row];
      *(us4*)&dst[term][bofs + kt * 2048 + (size_t)row * 32 + tin] = pk;
    }
  }
}

// ---------------------------------------------------------------------------
// 2b) QKV with FUSED SPLIT-K MERGE of the previous layer:
//     X_new = X_old + (O0*w0 + O1*w1)/(l0*w0 + l1*w1), w_i = e^(m_i - m).
//     Then identical qkv+split on X_new (also written back to X).
// ---------------------------------------------------------------------------
__global__ __launch_bounds__(256) void k_qkv_merge(
    float* __restrict__ X,
    const float* __restrict__ Mp, const float* __restrict__ Lp,
    const float* __restrict__ Op,
    const float* __restrict__ WQ, const float* __restrict__ WK,
    const float* __restrict__ WV,
    float* __restrict__ Q,
    unsigned short* __restrict__ Kh, unsigned short* __restrict__ Km,
    unsigned short* __restrict__ Kl,
    unsigned short* __restrict__ VhT, unsigned short* __restrict__ VmT,
    unsigned short* __restrict__ VlT) {
  __shared__ float xs[16][64];
  __shared__ unsigned short vs[3][16][64];
  const int c  = threadIdx.x & 63;
  const int tg = threadIdx.x >> 6;
  const size_t t0 = (size_t)blockIdx.x * 16;
  #pragma unroll
  for (int r = tg; r < 16; r += 4) {
    const size_t grow = t0 + r;                 // global row 0..32767
    const float m0 = Mp[grow], m1 = Mp[32768 + grow];
    const float l0 = Lp[grow], l1 = Lp[32768 + grow];
    const float mm = fmaxf(m0, m1);
    const float w0 = __expf(m0 - mm), w1 = __expf(m1 - mm);
    const float inv = 1.0f / (l0 * w0 + l1 * w1);
    const float o0 = Op[grow * 64 + c];
    const float o1 = Op[(size_t)2097152 + grow * 64 + c];
    const float xn = X[grow * 64 + c] + (o0 * w0 + o1 * w1) * inv;
    X[grow * 64 + c] = xn;
    xs[r][c] = xn;
  }
  __syncthreads();
  float qa[4] = {0.f,0.f,0.f,0.f};
  float ka[4] = {0.f,0.f,0.f,0.f};
  float va[4] = {0.f,0.f,0.f,0.f};
  for (int j = 0; j < 64; ++j) {
    const float wq = WQ[j * 64 + c];
    const float wk = WK[j * 64 + c];
    const float wv = WV[j * 64 + c];
    #pragma unroll
    for (int r = 0; r < 4; ++r) {
      const float x = xs[tg * 4 + r][j];
      qa[r] = fmaf(x, wq, qa[r]);
      ka[r] = fmaf(x, wk, ka[r]);
      va[r] = fmaf(x, wv, va[r]);
    }
  }
  #pragma unroll
  for (int r = 0; r < 4; ++r) {
    const int t = tg * 4 + r;
    const size_t idx = (t0 + t) * 64 + c;
    Q[idx] = qa[r];
    unsigned short h, m, l;
    split3(ka[r], h, m, l);
    Kh[idx] = h; Km[idx] = m; Kl[idx] = l;
    split3(va[r], h, m, l);
    vs[0][t][c] = h; vs[1][t][c] = m; vs[2][t][c] = l;
  }
  __syncthreads();
  {
    const int row  = threadIdx.x >> 2;
    const int part = threadIdx.x & 3;
    const size_t bofs = (t0 >> 10) * ((size_t)DIMN * 64);
    const size_t kt   = (t0 & 1023) >> 5;
    const size_t tin  = (t0 & 31) + part * 4;
    unsigned short* dst[3] = {VhT, VmT, VlT};
    #pragma unroll
    for (int term = 0; term < 3; ++term) {
      us4 pk;
      #pragma unroll
      for (int i = 0; i < 4; ++i) pk[i] = vs[term][part * 4 + i][row];
      *(us4*)&dst[term][bofs + kt * 2048 + (size_t)row * 32 + tin] = pk;
    }
  }
}

// ---------------------------------------------------------------------------
// 3) MFMA flash attention, SPLIT-K (2 halves): grid 1024 -> 4 blocks/CU =
//    16 waves/CU (2x r8's 8; r6<->r8 showed time tracks waves/CU).
//    Each block: r8's exact per-tile arithmetic over 16 of the 32 key tiles,
//    XCD-swizzled (batch pinned to one XCD). Writes partial (m, l, raw O);
//    merge happens in the next layer's k_qkv_merge / k_merge_mean.
//    LDS 38.4 KB x 4 = 153.6 <= 160 KB; VGPR 80 <= 128 (launch_bounds 256,4).
// ---------------------------------------------------------------------------
__global__ __launch_bounds__(256, 4) void k_attn_sk(
    const float* __restrict__ Qg,
    const unsigned short* __restrict__ Kh, const unsigned short* __restrict__ Km,
    const unsigned short* __restrict__ Kl,
    const unsigned short* __restrict__ VhT, const unsigned short* __restrict__ VmT,
    const unsigned short* __restrict__ VlT,
    float* __restrict__ Mp, float* __restrict__ Lp, float* __restrict__ Op) {
  __shared__ __align__(16) unsigned short Khs[32 * 72];
  __shared__ __align__(16) unsigned short Kms[32 * 72];
  __shared__ __align__(16) unsigned short Kls[32 * 72];
  __shared__ __align__(16) unsigned short Vhs[64 * 40];   // V^T: [c][j]
  __shared__ __align__(16) unsigned short Vms[64 * 40];
  __shared__ __align__(16) unsigned short Vls[64 * 40];
  __shared__ __align__(16) float Pb[64 * 36];             // fp32 P round-trip

  const int tid  = threadIdx.x;
  const int w    = tid >> 6;
  const int lane = tid & 63;
  const int ln   = lane & 15;
  const int q    = lane >> 4;

  // XCD-aware swizzle: 1024 blocks; batch pinned to one XCD (locality only)
  const int bid   = blockIdx.x;            // 0..1023
  const int xcd   = bid & 7;
  const int seq   = bid >> 3;              // 0..127
  const int b     = xcd * 4 + (seq >> 5);  // 4 batches per XCD
  const int local = seq & 31;
  const int half  = local >> 4;            // K-split half
  const int i0    = (local & 15) * 64;     // Q tile

  const size_t base = (size_t)b * (DIMN * 64);
  const float scale = 0.03125f;

  const int kj = tid >> 3, kg = tid & 7;
  const int vc = tid >> 2, vg = tid & 3;
  const int klo = kj * 72 + kg * 8;
  const int vlo = vc * 40 + vg * 8;

  // ---- Q fragments: 3-term split, 2 k-chunks (once per block) --------------
  bf16x8 qh[2], qm[2], ql[2];
  {
    const int mrow = i0 + 16 * w + ln;
    const float* qp = Qg + base + (size_t)mrow * 64 + 8 * q;
    #pragma unroll
    for (int s = 0; s < 2; ++s) {
      const float4 x0 = ((const float4*)(qp + 32 * s))[0];
      const float4 x1 = ((const float4*)(qp + 32 * s))[1];
      const float xv[8] = {x0.x, x0.y, x0.z, x0.w, x1.x, x1.y, x1.z, x1.w};
      union { bf16x8 v; unsigned short e[8]; } uh, um, ul;
      #pragma unroll
      for (int j = 0; j < 8; ++j) {
        unsigned short h, m, l;
        split3(xv[j], h, m, l);
        uh.e[j] = h; um.e[j] = m; ul.e[j] = l;
      }
      qh[s] = uh.v; qm[s] = um.v; ql[s] = ul.v;
    }
  }

  f32x4 O[4];
  #pragma unroll
  for (int ct = 0; ct < 4; ++ct) O[ct] = (f32x4){0.f, 0.f, 0.f, 0.f};
  float m_run[4] = {-INFINITY, -INFINITY, -INFINITY, -INFINITY};
  float l_run[4] = {0.f, 0.f, 0.f, 0.f};

  const int kt0 = half * 16;
  for (int kt = kt0; kt < kt0 + 16; ++kt) {
    __syncthreads();   // previous iteration's K/V readers done

    // ---- stage pre-split K/V tile: pure 16B copies -------------------------
    {
      const size_t tof = base + (size_t)kt * 2048 + tid * 8;  // shorts
      const us8 a0 = *(const us8*)&Kh[tof];
      const us8 a1 = *(const us8*)&Km[tof];
      const us8 a2 = *(const us8*)&Kl[tof];
      const us8 b0 = *(const us8*)&VhT[tof];
      const us8 b1 = *(const us8*)&VmT[tof];
      const us8 b2 = *(const us8*)&VlT[tof];
      *(us8*)&Khs[klo] = a0;
      *(us8*)&Kms[klo] = a1;
      *(us8*)&Kls[klo] = a2;
      *(us8*)&Vhs[vlo] = b0;
      *(us8*)&Vms[vlo] = b1;
      *(us8*)&Vls[vlo] = b2;
    }
    __syncthreads();

    // ---- S strip = Q . K^T via 6-product compensated MFMA (r5 order) -------
    f32x4 sacc[2];
    #pragma unroll
    for (int ct = 0; ct < 2; ++ct) {
      f32x4 a = (f32x4){0.f, 0.f, 0.f, 0.f};
      #pragma unroll
      for (int s = 0; s < 2; ++s) {
        const int ko = (16 * ct + ln) * 72 + 32 * s + 8 * q;
        const bf16x8 bh = ld16B(&Khs[ko]);
        const bf16x8 bm = ld16B(&Kms[ko]);
        const bf16x8 bl = ld16B(&Kls[ko]);
        a = MFMA16(ql[s], bh, a);
        a = MFMA16(qh[s], bl, a);
        a = MFMA16(qm[s], bm, a);
        a = MFMA16(qm[s], bh, a);
        a = MFMA16(qh[s], bm, a);
        a = MFMA16(qh[s], bh, a);
      }
      sacc[ct] = a;
    }

    // ---- wave-local online softmax (r5-identical per half) -----------------
    float rmax[4];
    #pragma unroll
    for (int r = 0; r < 4; ++r)
      rmax[r] = fmaxf(sacc[0][r], sacc[1][r]);
    #pragma unroll
    for (int mk = 1; mk <= 8; mk <<= 1) {
      #pragma unroll
      for (int r = 0; r < 4; ++r)
        rmax[r] = fmaxf(rmax[r], __shfl_xor(rmax[r], mk, 64));
    }
    float alpha[4], rsum[4];
    #pragma unroll
    for (int r = 0; r < 4; ++r) {
      const float mnew = fmaxf(m_run[r], rmax[r] * scale);
      alpha[r] = __expf(m_run[r] - mnew);
      m_run[r] = mnew;
      rsum[r] = 0.f;
    }
    #pragma unroll
    for (int ct = 0; ct < 2; ++ct) {
      #pragma unroll
      for (int r = 0; r < 4; ++r) {
        const float pv = __expf(sacc[ct][r] * scale - m_run[r]);
        rsum[r] += pv;
        Pb[(16 * w + 4 * q + r) * 36 + ln + 16 * ct] = pv;   // fp32, wave-local
      }
    }
    #pragma unroll
    for (int mk = 1; mk <= 8; mk <<= 1) {
      #pragma unroll
      for (int r = 0; r < 4; ++r)
        rsum[r] += __shfl_xor(rsum[r], mk, 64);
    }
    #pragma unroll
    for (int r = 0; r < 4; ++r)
      l_run[r] = l_run[r] * alpha[r] + rsum[r];

    #pragma unroll
    for (int ct = 0; ct < 4; ++ct) {
      #pragma unroll
      for (int r = 0; r < 4; ++r) O[ct][r] *= alpha[r];
    }

    // ---- P A-fragment: own rows, fp32 -> 3-term split ----------------------
    bf16x8 ph, pm, pl;
    {
      const float* pp = &Pb[(16 * w + ln) * 36 + 8 * q];
      const float4 p0 = ((const float4*)pp)[0];
      const float4 p1 = ((const float4*)pp)[1];
      const float pvv[8] = {p0.x, p0.y, p0.z, p0.w, p1.x, p1.y, p1.z, p1.w};
      union { bf16x8 v; unsigned short e[8]; } uh, um, ul;
      #pragma unroll
      for (int j = 0; j < 8; ++j) {
        unsigned short h, m, l;
        split3(pvv[j], h, m, l);
        uh.e[j] = h; um.e[j] = m; ul.e[j] = l;
      }
      ph = uh.v; pm = um.v; pl = ul.v;
    }

    // ---- O += P @ V, 6-product (r5 order) ----------------------------------
    #pragma unroll
    for (int ct = 0; ct < 4; ++ct) {
      const int vo = (16 * ct + ln) * 40 + 8 * q;
      const bf16x8 vvh = ld16B(&Vhs[vo]);
      const bf16x8 vvm = ld16B(&Vms[vo]);
      const bf16x8 vvl = ld16B(&Vls[vo]);
      O[ct] = MFMA16(ph, vvh, O[ct]);
      O[ct] = MFMA16(ph, vvm, O[ct]);
      O[ct] = MFMA16(pm, vvh, O[ct]);
      O[ct] = MFMA16(pm, vvm, O[ct]);
      O[ct] = MFMA16(ph, vvl, O[ct]);
      O[ct] = MFMA16(pl, vvh, O[ct]);
    }
  }

  // ---- epilogue: write split-K partials (m, l, raw O) ----------------------
  const size_t hofs = (size_t)half * (32 * 1024);
  #pragma unroll
  for (int r = 0; r < 4; ++r) {
    const int row = i0 + 16 * w + 4 * q + r;
    const size_t grow = hofs + (size_t)b * DIMN + row;
    #pragma unroll
    for (int ct = 0; ct < 4; ++ct)
      Op[grow * 64 + ln + 16 * ct] = O[ct][r];
    if (ln == 0) { Mp[grow] = m_run[r]; Lp[grow] = l_run[r]; }
  }
}

// ---------------------------------------------------------------------------
// 3b) final merge + channel-mean (layer 7 partials): 256 blocks x 128 tokens
// ---------------------------------------------------------------------------
__global__ __launch_bounds__(256) void k_merge_mean(
    const float* __restrict__ X,
    const float* __restrict__ Mp, const float* __restrict__ Lp,
    const float* __restrict__ Op, float* __restrict__ meanv) {
  const int c  = threadIdx.x & 63;
  const int tg = threadIdx.x >> 6;
  const size_t t0 = (size_t)blockIdx.x * 128;
  for (int i = tg; i < 128; i += 4) {
    const size_t grow = t0 + i;
    const float m0 = Mp[grow], m1 = Mp[32768 + grow];
    const float l0 = Lp[grow], l1 = Lp[32768 + grow];
    const float mm = fmaxf(m0, m1);
    const float w0 = __expf(m0 - mm), w1 = __expf(m1 - mm);
    const float inv = 1.0f / (l0 * w0 + l1 * w1);
    const float o0 = Op[grow * 64 + c];
    const float o1 = Op[(size_t)2097152 + grow * 64 + c];
    float v = X[grow * 64 + c] + (o0 * w0 + o1 * w1) * inv;
    #pragma unroll
    for (int off = 32; off > 0; off >>= 1)
      v += __shfl_down(v, off, 64);
    if (c == 0) meanv[grow] = v * (1.0f / 64.0f);
  }
}

// ---------------------------------------------------------------------------
// 4) head stage 2: pred[b,k] = meanv[b,:] . last_W[k,:] + last_b[k]
// ---------------------------------------------------------------------------
__global__ __launch_bounds__(256) void k_head2(
    const float* __restrict__ meanv, const float* __restrict__ lW,
    const float* __restrict__ lb, float* __restrict__ out) {
  __shared__ float red[256];
  const int b   = blockIdx.x;
  const int tid = threadIdx.x;
  float acc[NCLS];
  #pragma unroll
  for (int k = 0; k < NCLS; ++k) acc[k] = 0.f;
  for (int n = tid; n < DIMN; n += 256) {
    const float m = meanv[(size_t)b * DIMN + n];
    #pragma unroll
    for (int k = 0; k < NCLS; ++k)
      acc[k] = fmaf(m, lW[k * DIMN + n], acc[k]);
  }
  for (int k = 0; k < NCLS; ++k) {
    red[tid] = acc[k];
    __syncthreads();
    for (int s = 128; s > 0; s >>= 1) {
      if (tid < s) red[tid] += red[tid + s];
      __syncthreads();
    }
    if (tid == 0) out[b * NCLS + k] = red[0] + lb[k];
    __syncthreads();
  }
}

// ===========================================================================
// MIDDLE-TIER PATH (r8 kernel, ws >= 41 MB but < split-K need): proven 0.0
// ===========================================================================
__global__ __launch_bounds__(256) void k_attn_s(
    const float* __restrict__ Qg,
    const unsigned short* __restrict__ Kh, const unsigned short* __restrict__ Km,
    const unsigned short* __restrict__ Kl,
    const unsigned short* __restrict__ VhT, const unsigned short* __restrict__ VmT,
    const unsigned short* __restrict__ VlT,
    float* __restrict__ X, float* __restrict__ meanout) {
  __shared__ __align__(16) unsigned short Khs[32 * 72];
  __shared__ __align__(16) unsigned short Kms[32 * 72];
  __shared__ __align__(16) unsigned short Kls[32 * 72];
  __shared__ __align__(16) unsigned short Vhs[64 * 40];
  __shared__ __align__(16) unsigned short Vms[64 * 40];
  __shared__ __align__(16) unsigned short Vls[64 * 40];
  __shared__ __align__(16) float Pb[64 * 36];

  const int tid  = threadIdx.x;
  const int w    = tid >> 6;
  const int lane = tid & 63;
  const int ln   = lane & 15;
  const int q    = lane >> 4;
  const int bid = blockIdx.x;
  const int xcd = bid & 7;
  const int seq = bid >> 3;
  const int b   = xcd * 4 + (seq >> 4);
  const int i0  = (seq & 15) * 64;
  const size_t base = (size_t)b * (DIMN * 64);
  const float scale = 0.03125f;

  const int kj = tid >> 3, kg = tid & 7;
  const int vc = tid >> 2, vg = tid & 3;
  const int klo = kj * 72 + kg * 8;
  const int vlo = vc * 40 + vg * 8;

  bf16x8 qh[2], qm[2], ql[2];
  {
    const int mrow = i0 + 16 * w + ln;
    const float* qp = Qg + base + (size_t)mrow * 64 + 8 * q;
    #pragma unroll
    for (int s = 0; s < 2; ++s) {
      const float4 x0 = ((const float4*)(qp + 32 * s))[0];
      const float4 x1 = ((const float4*)(qp + 32 * s))[1];
      const float xv[8] = {x0.x, x0.y, x0.z, x0.w, x1.x, x1.y, x1.z, x1.w};
      union { bf16x8 v; unsigned short e[8]; } uh, um, ul;
      #pragma unroll
      for (int j = 0; j < 8; ++j) {
        unsigned short h, m, l;
        split3(xv[j], h, m, l);
        uh.e[j] = h; um.e[j] = m; ul.e[j] = l;
      }
      qh[s] = uh.v; qm[s] = um.v; ql[s] = ul.v;
    }
  }

  f32x4 O[4];
  #pragma unroll
  for (int ct = 0; ct < 4; ++ct) O[ct] = (f32x4){0.f, 0.f, 0.f, 0.f};
  float m_run[4] = {-INFINITY, -INFINITY, -INFINITY, -INFINITY};
  float l_run[4] = {0.f, 0.f, 0.f, 0.f};

  for (int kt = 0; kt < 32; ++kt) {
    __syncthreads();
    {
      const size_t tof = base + (size_t)kt * 2048 + tid * 8;
      const us8 a0 = *(const us8*)&Kh[tof];
      const us8 a1 = *(const us8*)&Km[tof];
      const us8 a2 = *(const us8*)&Kl[tof];
      const us8 b0 = *(const us8*)&VhT[tof];
      const us8 b1 = *(const us8*)&VmT[tof];
      const us8 b2 = *(const us8*)&VlT[tof];
      *(us8*)&Khs[klo] = a0;
      *(us8*)&Kms[klo] = a1;
      *(us8*)&Kls[klo] = a2;
      *(us8*)&Vhs[vlo] = b0;
      *(us8*)&Vms[vlo] = b1;
      *(us8*)&Vls[vlo] = b2;
    }
    __syncthreads();

    f32x4 sacc[2];
    #pragma unroll
    for (int ct = 0; ct < 2; ++ct) {
      f32x4 a = (f32x4){0.f, 0.f, 0.f, 0.f};
      #pragma unroll
      for (int s = 0; s < 2; ++s) {
        const int ko = (16 * ct + ln) * 72 + 32 * s + 8 * q;
        const bf16x8 bh = ld16B(&Khs[ko]);
        const bf16x8 bm = ld16B(&Kms[ko]);
        const bf16x8 bl = ld16B(&Kls[ko]);
        a = MFMA16(ql[s], bh, a);
        a = MFMA16(qh[s], bl, a);
        a = MFMA16(qm[s], bm, a);
        a = MFMA16(qm[s], bh, a);
        a = MFMA16(qh[s], bm, a);
        a = MFMA16(qh[s], bh, a);
      }
      sacc[ct] = a;
    }

    float rmax[4];
    #pragma unroll
    for (int r = 0; r < 4; ++r)
      rmax[r] = fmaxf(sacc[0][r], sacc[1][r]);
    #pragma unroll
    for (int mk = 1; mk <= 8; mk <<= 1) {
      #pragma unroll
      for (int r = 0; r < 4; ++r)
        rmax[r] = fmaxf(rmax[r], __shfl_xor(rmax[r], mk, 64));
    }
    float alpha[4], rsum[4];
    #pragma unroll
    for (int r = 0; r < 4; ++r) {
      const float mnew = fmaxf(m_run[r], rmax[r] * scale);
      alpha[r] = __expf(m_run[r] - mnew);
      m_run[r] = mnew;
      rsum[r] = 0.f;
    }
    #pragma unroll
    for (int ct = 0; ct < 2; ++ct) {
      #pragma unroll
      for (int r = 0; r < 4; ++r) {
        const float pv = __expf(sacc[ct][r] * scale - m_run[r]);
        rsum[r] += pv;
        Pb[(16 * w + 4 * q + r) * 36 + ln + 16 * ct] = pv;
      }
    }
    #pragma unroll
    for (int mk = 1; mk <= 8; mk <<= 1) {
      #pragma unroll
      for (int r = 0; r < 4; ++r)
        rsum[r] += __shfl_xor(rsum[r], mk, 64);
    }
    #pragma unroll
    for (int r = 0; r < 4; ++r)
      l_run[r] = l_run[r] * alpha[r] + rsum[r];

    #pragma unroll
    for (int ct = 0; ct < 4; ++ct) {
      #pragma unroll
      for (int r = 0; r < 4; ++r) O[ct][r] *= alpha[r];
    }

    bf16x8 ph, pm, pl;
    {
      const float* pp = &Pb[(16 * w + ln) * 36 + 8 * q];
      const float4 p0 = ((const float4*)pp)[0];
      const float4 p1 = ((const float4*)pp)[1];
      const float pvv[8] = {p0.x, p0.y, p0.z, p0.w, p1.x, p1.y, p1.z, p1.w};
      union { bf16x8 v; unsigned short e[8]; } uh, um, ul;
      #pragma unroll
      for (int j = 0; j < 8; ++j) {
        unsigned short h, m, l;
        split3(pvv[j], h, m, l);
        uh.e[j] = h; um.e[j] = m; ul.e[j] = l;
      }
      ph = uh.v; pm = um.v; pl = ul.v;
    }

    #pragma unroll
    for (int ct = 0; ct < 4; ++ct) {
      const int vo = (16 * ct + ln) * 40 + 8 * q;
      const bf16x8 vvh = ld16B(&Vhs[vo]);
      const bf16x8 vvm = ld16B(&Vms[vo]);
      const bf16x8 vvl = ld16B(&Vls[vo]);
      O[ct] = MFMA16(ph, vvh, O[ct]);
      O[ct] = MFMA16(ph, vvm, O[ct]);
      O[ct] = MFMA16(pm, vvh, O[ct]);
      O[ct] = MFMA16(pm, vvm, O[ct]);
      O[ct] = MFMA16(ph, vvl, O[ct]);
      O[ct] = MFMA16(pl, vvh, O[ct]);
    }
  }

  float linv[4];
  #pragma unroll
  for (int r = 0; r < 4; ++r) linv[r] = 1.0f / l_run[r];
  #pragma unroll
  for (int r = 0; r < 4; ++r) {
    const int row = i0 + 16 * w + 4 * q + r;
    float srow = 0.f;
    #pragma unroll
    for (int ct = 0; ct < 4; ++ct) {
      float* xp = X + base + (size_t)row * 64 + ln + 16 * ct;
      const float nv = *xp + O[ct][r] * linv[r];
      *xp = nv;
      srow += nv;
    }
    if (meanout) {
      #pragma unroll
      for (int mk = 1; mk <= 8; mk <<= 1)
        srow += __shfl_xor(srow, mk, 64);
      if (ln == 0) meanout[(size_t)b * DIMN + row] = srow * (1.0f / 64.0f);
    }
  }
}

// ---------------------------------------------------------------------------
// launch
// ---------------------------------------------------------------------------
extern "C" void kernel_launch(void* const* d_in, const int* in_sizes, int n_in,
                              void* d_out, int out_size, void* d_ws, size_t ws_size,
                              hipStream_t stream) {
  const float* image = (const float*)d_in[0];
  const float* WV    = (const float*)d_in[1];
  const float* WK    = (const float*)d_in[2];
  const float* WQ    = (const float*)d_in[3];
  const float* lW    = (const float*)d_in[4];
  const float* lb    = (const float*)d_in[5];
  float* out = (float*)d_out;

  float* ws = (float*)d_ws;
  const size_t NELEM = (size_t)BB * DIMN * CCH;   // 2,097,152
  const size_t NROW  = (size_t)BB * DIMN;         // 32,768

  // layout (floats): X | Q | KVsplits(3N) | Op(2N) | Mp(2R) | Lp(2R) | meanv(R)
  const size_t need_sk   = (7 * NELEM + 5 * NROW) * sizeof(float);
  const size_t need_fast = (5 * NELEM + NROW) * sizeof(float);

  if (ws_size >= need_sk) {
    float* X = ws;
    float* Q = ws + NELEM;
    unsigned short* Kh  = (unsigned short*)(ws + 2 * NELEM);
    unsigned short* Km  = Kh + NELEM;
    unsigned short* Kl  = Kh + 2 * NELEM;
    unsigned short* VhT = Kh + 3 * NELEM;
    unsigned short* VmT = Kh + 4 * NELEM;
    unsigned short* VlT = Kh + 5 * NELEM;
    float* Op    = ws + 5 * NELEM;
    float* Mp    = ws + 7 * NELEM;
    float* Lp    = Mp + 2 * NROW;
    float* meanv = Lp + 2 * NROW;

    k_transpose<<<dim3(DIMN / 64, BB), 256, 0, stream>>>(image, X);
    k_qkv_split<<<(BB * DIMN) / 16, 256, 0, stream>>>(
        X, WQ, WK, WV, Q, Kh, Km, Kl, VhT, VmT, VlT);
    for (int layer = 0; layer < 8; ++layer) {
      k_attn_sk<<<1024, 256, 0, stream>>>(
          Q, Kh, Km, Kl, VhT, VmT, VlT, Mp, Lp, Op);
      if (layer < 7)
        k_qkv_merge<<<(BB * DIMN) / 16, 256, 0, stream>>>(
            X, Mp, Lp, Op, WQ, WK, WV, Q, Kh, Km, Kl, VhT, VmT, VlT);
    }
    k_merge_mean<<<256, 256, 0, stream>>>(X, Mp, Lp, Op, meanv);
    k_head2<<<BB, 256, 0, stream>>>(meanv, lW, lb, out);
  } else {
    // middle tier: r8 path (proven absmax 0.0)
    float* X = ws;
    float* Q = ws + NELEM;
    unsigned short* Kh  = (unsigned short*)(ws + 2 * NELEM);
    unsigned short* Km  = Kh + NELEM;
    unsigned short* Kl  = Kh + 2 * NELEM;
    unsigned short* VhT = Kh + 3 * NELEM;
    unsigned short* VmT = Kh + 4 * NELEM;
    unsigned short* VlT = Kh + 5 * NELEM;
    float* meanv = ws + 5 * NELEM;
    (void)need_fast;

    k_transpose<<<dim3(DIMN / 64, BB), 256, 0, stream>>>(image, X);
    for (int layer = 0; layer < 8; ++layer) {
      k_qkv_split<<<(BB * DIMN) / 16, 256, 0, stream>>>(
          X, WQ, WK, WV, Q, Kh, Km, Kl, VhT, VmT, VlT);
      k_attn_s<<<512, 256, 0, stream>>>(
          Q, Kh, Km, Kl, VhT, VmT, VlT, X, (layer == 7) ? meanv : nullptr);
    }
    k_head2<<<BB, 256, 0, stream>>>(meanv, lW, lb, out);
  }
}